// Round 14
// baseline (198.679 us; speedup 1.0000x reference)
//
#include <hip/hip_runtime.h>
#include <hip/hip_bf16.h>

// RAYEN ConstraintModule for MI355X (gfx950) — R13.
// B=32768, IN_DIM=256, N=K=128, M_LIN=1024, QC=16. f32 buffers (flag==0 path).
// R12 post-mortem: occupancy is NOT k2b's limiter (Occ 40% was SLOWER than 17.6%).
// k2b perf tracks MFMA-per-wave amortization (R7:32/87us, R12:64/76us, R10:128/54us).
// R13: k2b reverted to rt=4 (256,2) + TWO q per wave (256 MFMA/wave, half the WGs,
// one rho-stage per 2 q) + explicit 2-deep register double-buffer on delta loads.

typedef __attribute__((ext_vector_type(8))) short short8;
typedef __attribute__((ext_vector_type(4))) float f32x4;
typedef __attribute__((ext_vector_type(4))) unsigned short us4;

__device__ __forceinline__ float bf2f(unsigned short u) {
    union { unsigned int i; float f; } v; v.i = ((unsigned int)u) << 16; return v.f;
}
__device__ __forceinline__ unsigned short f2bf(float f) {
    union { float f; unsigned int i; } v; v.f = f;
    unsigned int r = v.i + 0x7FFFu + ((v.i >> 16) & 1u);  // RNE
    return (unsigned short)(r >> 16);
}

template<int DT>
__device__ __forceinline__ short8 ld8(const void* p, size_t i) {
    if constexpr (DT == 1) {
        return *reinterpret_cast<const short8*>(reinterpret_cast<const unsigned short*>(p) + i);
    } else {
        const float* f = reinterpret_cast<const float*>(p) + i;
        short8 r;
#pragma unroll
        for (int j = 0; j < 8; ++j) r[j] = (short)f2bf(f[j]);
        return r;
    }
}
template<int DT>
__device__ __forceinline__ float ldf(const void* p, int i) {
    if constexpr (DT == 1) return bf2f(reinterpret_cast<const unsigned short*>(p)[i]);
    else return reinterpret_cast<const float*>(p)[i];
}

// 8 consecutive f32 -> short8 bf16, via two vector loads
__device__ __forceinline__ short8 ld8f4(const float* f) {
    f32x4 a = *reinterpret_cast<const f32x4*>(f);
    f32x4 b = *reinterpret_cast<const f32x4*>(f + 4);
    short8 r;
#pragma unroll
    for (int j = 0; j < 4; ++j) { r[j] = (short)f2bf(a[j]); r[4 + j] = (short)f2bf(b[j]); }
    return r;
}

__device__ __forceinline__ void glds16(const void* g, void* l) {
    __builtin_amdgcn_global_load_lds(
        (const __attribute__((address_space(1))) void*)g,
        (__attribute__((address_space(3))) void*)l, 16, 0, 0);
}

__global__ void detect_dtype(const unsigned short* __restrict__ x, int* __restrict__ flag) {
    __shared__ int cnt;
    if (threadIdx.x == 0) cnt = 0;
    __syncthreads();
    float a = fabsf(bf2f(x[threadIdx.x]));
    int ok = (a > 1e-3f && a < 1e2f) ? 1 : 0;
    atomicAdd(&cnt, ok);
    __syncthreads();
    if (threadIdx.x == 0) *flag = (cnt > 200) ? 1 : 0;  // 1 = bf16, 0 = f32
}

// ===== cvt_const: W/D/delta/phi -> bf16 in ws (convert if f32, copy if bf16) =====
__global__ void cvt_const(
    const void* __restrict__ Wp, const void* __restrict__ Dp,
    const void* __restrict__ Qp, const void* __restrict__ Pp,
    unsigned short* __restrict__ Wb, unsigned short* __restrict__ Db,
    unsigned short* __restrict__ Qb, unsigned short* __restrict__ Pb,
    const int* __restrict__ flag)
{
    const int nW = 32768, nD = 131072, nQ = 262144, nP = 2048;
    int idx = blockIdx.x * 256 + threadIdx.x;      // 4 elems per thread
    int e = idx * 4;
    if (e >= nW + nD + nQ + nP) return;
    const void* src; unsigned short* dst; int off;
    if      (e < nW)           { src = Wp; dst = Wb; off = e; }
    else if (e < nW + nD)      { src = Dp; dst = Db; off = e - nW; }
    else if (e < nW + nD + nQ) { src = Qp; dst = Qb; off = e - nW - nD; }
    else                       { src = Pp; dst = Pb; off = e - nW - nD - nQ; }
    us4 out;
    if (*flag == 0) {
        f32x4 v = *reinterpret_cast<const f32x4*>(reinterpret_cast<const float*>(src) + off);
#pragma unroll
        for (int j = 0; j < 4; ++j) out[j] = f2bf(v[j]);
    } else {
        out = *reinterpret_cast<const us4*>(reinterpret_cast<const unsigned short*>(src) + off);
    }
    *reinterpret_cast<us4*>(dst + off) = out;
}

// ========== K1: v_bar -> rho (bf16, ws), kappa seeded with 1/norm ==========
template<int DT>
__global__ __launch_bounds__(256, 2) void k1_vbar(
    const void* __restrict__ xp, const unsigned short* __restrict__ Wb,
    const void* __restrict__ bp,
    unsigned short* __restrict__ rho_g, unsigned int* __restrict__ kap_u,
    const int* __restrict__ flag)
{
    if (*flag != DT) return;
    __shared__ unsigned char lds_x[32768];   // x tile bf16, frag-major
    __shared__ unsigned char lds_v[16384];   // v_bar [64][256B] unswizzled
    __shared__ float lds_nsq[64][4];

    const int tid = threadIdx.x;
    const int lane = tid & 63;
    const int w = tid >> 6, hi = lane >> 4, lo = lane & 15;
    const size_t row0 = (size_t)blockIdx.x * 64;

    // stage x tile [64][256] -> bf16 frag-major LDS
#pragma unroll
    for (int i = 0; i < 8; ++i) {
        int ch = i * 256 + tid;
        int row = ((ch >> 9) << 4) | (ch & 15);
        int off = (((ch >> 6) & 7) << 6) | (((ch >> 4) & 3) << 4);   // byte in 512B bf16 row
        if constexpr (DT == 1) {
            glds16((const unsigned char*)xp + (row0 + row) * 512 + off, lds_x + ch * 16);
        } else {
            const float* src = (const float*)xp + (row0 + row) * 256 + (off >> 1);
            *reinterpret_cast<short8*>(lds_x + ch * 16) = ld8f4(src);
        }
    }
    // W fragments from converted bf16 (overlaps staging)
    short8 wf[2][8];
#pragma unroll
    for (int ct = 0; ct < 2; ++ct)
#pragma unroll
        for (int kb = 0; kb < 8; ++kb)
            wf[ct][kb] = *reinterpret_cast<const short8*>(
                Wb + (size_t)(w * 32 + ct * 16 + lo) * 256 + kb * 32 + hi * 8);
    if constexpr (DT == 1) { asm volatile("s_waitcnt vmcnt(0)" ::: "memory"); }
    __syncthreads();

    f32x4 acc1[2][4];
#pragma unroll
    for (int c = 0; c < 2; ++c)
#pragma unroll
        for (int r = 0; r < 4; ++r)
#pragma unroll
            for (int e = 0; e < 4; ++e) acc1[c][r][e] = 0.f;
#pragma unroll
    for (int kb = 0; kb < 8; ++kb) {
        short8 af[4];
#pragma unroll
        for (int rt = 0; rt < 4; ++rt)
            af[rt] = *reinterpret_cast<const short8*>(lds_x + (((rt << 3) | kb) << 10) + lane * 16);
#pragma unroll
        for (int ct = 0; ct < 2; ++ct)
#pragma unroll
            for (int rt = 0; rt < 4; ++rt)
                acc1[ct][rt] = __builtin_amdgcn_mfma_f32_16x16x32_bf16(af[rt], wf[ct][kb], acc1[ct][rt], 0, 0, 0);
    }
    float bv[2];
#pragma unroll
    for (int ct = 0; ct < 2; ++ct) bv[ct] = ldf<DT>(bp, w * 32 + ct * 16 + lo);
#pragma unroll
    for (int rt = 0; rt < 4; ++rt)
#pragma unroll
        for (int reg = 0; reg < 4; ++reg) {
            float s = 0.f;
#pragma unroll
            for (int ct = 0; ct < 2; ++ct) {
                float v = acc1[ct][rt][reg] + bv[ct];
                acc1[ct][rt][reg] = v;
                s += v * v;
            }
            s += __shfl_xor(s, 1); s += __shfl_xor(s, 2);
            s += __shfl_xor(s, 4); s += __shfl_xor(s, 8);
            if (lo == 0) lds_nsq[rt * 16 + hi * 4 + reg][w] = s;
        }
    __syncthreads();

#pragma unroll
    for (int rt = 0; rt < 4; ++rt)
#pragma unroll
        for (int reg = 0; reg < 4; ++reg) {
            int row = rt * 16 + hi * 4 + reg;
            float nsq = lds_nsq[row][0] + lds_nsq[row][1] + lds_nsq[row][2] + lds_nsq[row][3];
            float rinv = 1.0f / fmaxf(sqrtf(nsq), 1e-12f);
#pragma unroll
            for (int ct = 0; ct < 2; ++ct) {
                int col = w * 32 + ct * 16 + lo;
                *reinterpret_cast<unsigned short*>(lds_v + row * 256 + col * 2) =
                    f2bf(acc1[ct][rt][reg] * rinv);
            }
        }
    if (tid < 64) {
        float nsq = lds_nsq[tid][0] + lds_nsq[tid][1] + lds_nsq[tid][2] + lds_nsq[tid][3];
        // alpha = min(1/kappa, norm) == 1/max(kappa, 1/norm): seed kappa with 1/norm
        kap_u[row0 + tid] = __float_as_uint(1.0f / sqrtf(nsq));
    }
    __syncthreads();
#pragma unroll
    for (int i = 0; i < 4; ++i) {
        int ch = i * 256 + tid;
        int row = ch >> 4, c16 = ch & 15;
        *reinterpret_cast<short8*>(rho_g + (row0 + row) * 128 + c16 * 8) =
            *reinterpret_cast<const short8*>(lds_v + row * 256 + c16 * 16);
    }
}

// ---- stage rho tile [64][128]bf16 into XOR-swizzled LDS ----
__device__ __forceinline__ void stage_rho(const unsigned short* rho_g, size_t row0,
                                          unsigned char* lds_rho, int tid) {
#pragma unroll
    for (int i = 0; i < 4; ++i) {
        int ch = i * 256 + tid;
        int row = ch >> 4;
        int off = (ch & 15) * 16;
        glds16((const unsigned char*)rho_g + (row0 + row) * 256 + (off ^ ((row & 7) << 4)),
               lds_rho + ch * 16);
    }
}

// ==== K2a: relu(max_m Dv) per (tile, mg) -> atomicMax kappa ====
__global__ __launch_bounds__(256, 4) void k2a_dmax(
    const unsigned short* __restrict__ Db, const unsigned short* __restrict__ rho_g,
    unsigned int* __restrict__ kap_u)
{
    __shared__ unsigned char lds_rho[16384];
    __shared__ float lds_red[64][4];
    const int tid = threadIdx.x;
    const int lane = tid & 63;
    const int w = tid >> 6, hi = lane >> 4, lo = lane & 15;
    const size_t row0 = (size_t)blockIdx.x * 64;
    const int mg = blockIdx.y;

    stage_rho(rho_g, row0, lds_rho, tid);
    asm volatile("s_waitcnt vmcnt(0)" ::: "memory");
    __syncthreads();

    short8 af2[4][4];
#pragma unroll
    for (int rt = 0; rt < 4; ++rt)
#pragma unroll
        for (int kb = 0; kb < 4; ++kb) {
            int row = rt * 16 + lo;
            af2[rt][kb] = *reinterpret_cast<const short8*>(
                lds_rho + row * 256 + (((kb << 6) | (hi << 4)) ^ ((lo & 7) << 4)));
        }

    f32x4 dmax[4];
#pragma unroll
    for (int rt = 0; rt < 4; ++rt)
#pragma unroll
        for (int e = 0; e < 4; ++e) dmax[rt][e] = -3e38f;

#pragma unroll 2
    for (int t = 0; t < 4; ++t) {
        int col = mg * 256 + w * 64 + t * 16 + lo;
        short8 bD[4];
#pragma unroll
        for (int kb = 0; kb < 4; ++kb)
            bD[kb] = *reinterpret_cast<const short8*>(Db + (size_t)col * 128 + kb * 32 + hi * 8);
        f32x4 acc[4];
#pragma unroll
        for (int rt = 0; rt < 4; ++rt)
#pragma unroll
            for (int e = 0; e < 4; ++e) acc[rt][e] = 0.f;
#pragma unroll
        for (int kb = 0; kb < 4; ++kb)
#pragma unroll
            for (int rt = 0; rt < 4; ++rt)
                acc[rt] = __builtin_amdgcn_mfma_f32_16x16x32_bf16(af2[rt][kb], bD[kb], acc[rt], 0, 0, 0);
#pragma unroll
        for (int rt = 0; rt < 4; ++rt)
#pragma unroll
            for (int e = 0; e < 4; ++e) dmax[rt][e] = fmaxf(dmax[rt][e], acc[rt][e]);
    }
#pragma unroll
    for (int rt = 0; rt < 4; ++rt)
#pragma unroll
        for (int reg = 0; reg < 4; ++reg) {
            float m = dmax[rt][reg];
            m = fmaxf(m, __shfl_xor(m, 1)); m = fmaxf(m, __shfl_xor(m, 2));
            m = fmaxf(m, __shfl_xor(m, 4)); m = fmaxf(m, __shfl_xor(m, 8));
            if (lo == 0) lds_red[rt * 16 + hi * 4 + reg][w] = m;
        }
    __syncthreads();
    if (tid < 64) {
        float m = fmaxf(fmaxf(lds_red[tid][0], lds_red[tid][1]),
                        fmaxf(lds_red[tid][2], lds_red[tid][3]));
        m = fmaxf(m, 0.f);  // relu; also keeps uint-monotone encoding valid
        atomicMax(&kap_u[row0 + tid], __float_as_uint(m));
    }
}

// == K2b: kq for TWO q per wave; rt=4, 2-deep pipelined delta loads; atomicMax ==
__global__ __launch_bounds__(256, 2) void k2b_quad(
    const unsigned short* __restrict__ Qb, const unsigned short* __restrict__ Pb,
    const unsigned short* __restrict__ rho_g, unsigned int* __restrict__ kap_u)
{
    __shared__ unsigned char lds_rho[16384];
    const int tid = threadIdx.x;
    const int lane = tid & 63;
    const int w = tid >> 6, hi = lane >> 4, lo = lane & 15;
    const size_t row0 = (size_t)blockIdx.x * 64;

    stage_rho(rho_g, row0, lds_rho, tid);
    asm volatile("s_waitcnt vmcnt(0)" ::: "memory");
    __syncthreads();

    short8 af2[4][4];
#pragma unroll
    for (int rt = 0; rt < 4; ++rt)
#pragma unroll
        for (int kb = 0; kb < 4; ++kb) {
            int row = rt * 16 + lo;
            af2[rt][kb] = *reinterpret_cast<const short8*>(
                lds_rho + row * 256 + (((kb << 6) | (hi << 4)) ^ ((lo & 7) << 4)));
        }

#pragma unroll
    for (int qq = 0; qq < 2; ++qq) {
        const int q = blockIdx.y * 8 + qq * 4 + w;   // y in {0,1}: covers q 0..15
        const unsigned short* Qq = Qb + (size_t)q * 16384;

        f32x4 qsum[4], lsum[4];
#pragma unroll
        for (int rt = 0; rt < 4; ++rt)
#pragma unroll
            for (int e = 0; e < 4; ++e) { qsum[rt][e] = 0.f; lsum[rt][e] = 0.f; }

        short8 pf[2][4];
#pragma unroll
        for (int kb = 0; kb < 4; ++kb)
            pf[0][kb] = *reinterpret_cast<const short8*>(Qq + (size_t)lo * 128 + kb * 32 + hi * 8);

#pragma unroll
        for (int t = 0; t < 8; ++t) {
            const int cur = t & 1;
            if (t + 1 < 8) {
#pragma unroll
                for (int kb = 0; kb < 4; ++kb)
                    pf[cur ^ 1][kb] = *reinterpret_cast<const short8*>(
                        Qq + (size_t)((t + 1) * 16 + lo) * 128 + kb * 32 + hi * 8);
            }
            const int colk = t * 16 + lo;
            float phv = bf2f(Pb[q * 128 + colk]);
            f32x4 acc[4];
#pragma unroll
            for (int rt = 0; rt < 4; ++rt)
#pragma unroll
                for (int e = 0; e < 4; ++e) acc[rt][e] = 0.f;
#pragma unroll
            for (int kb = 0; kb < 4; ++kb)
#pragma unroll
                for (int rt = 0; rt < 4; ++rt)
                    acc[rt] = __builtin_amdgcn_mfma_f32_16x16x32_bf16(af2[rt][kb], pf[cur][kb], acc[rt], 0, 0, 0);
#pragma unroll
            for (int rt = 0; rt < 4; ++rt)
#pragma unroll
                for (int e = 0; e < 4; ++e) {
                    int row = rt * 16 + hi * 4 + e;
                    float rv = bf2f(*reinterpret_cast<const unsigned short*>(
                        lds_rho + row * 256 + ((colk * 2) ^ ((row & 7) << 4))));
                    qsum[rt][e] += acc[rt][e] * rv;
                    lsum[rt][e] += rv * phv;
                }
        }
#pragma unroll
        for (int rt = 0; rt < 4; ++rt)
#pragma unroll
            for (int reg = 0; reg < 4; ++reg) {
                float s = qsum[rt][reg];
                s += __shfl_xor(s, 1); s += __shfl_xor(s, 2);
                s += __shfl_xor(s, 4); s += __shfl_xor(s, 8);
                float l = lsum[rt][reg];
                l += __shfl_xor(l, 1); l += __shfl_xor(l, 2);
                l += __shfl_xor(l, 4); l += __shfl_xor(l, 8);
                if (lo == 0) {
                    float kq = fmaxf(l + sqrtf(fmaxf(s, 0.f)), 0.f);
                    atomicMax(&kap_u[row0 + rt * 16 + hi * 4 + reg], __float_as_uint(kq));
                }
            }
    }
}

// ========== K3: alpha = 1/kappa; y = z0 + alpha*rho + yp -> d_out ==========
template<int DT>
__global__ __launch_bounds__(256, 4) void k3_out(
    const unsigned int* __restrict__ kap_u, const unsigned short* __restrict__ rho_g,
    const void* __restrict__ z0p, const void* __restrict__ ypp,
    void* __restrict__ outp, const int* __restrict__ flag)
{
    if (*flag != DT) return;
    __shared__ float lds_alpha[64];
    const int tid = threadIdx.x;
    const size_t row0 = (size_t)blockIdx.x * 64;

    if (tid < 64)
        lds_alpha[tid] = 1.0f / __uint_as_float(kap_u[row0 + tid]);
    __syncthreads();
#pragma unroll
    for (int i = 0; i < 4; ++i) {
        int idx = tid + i * 256;
        int row = idx >> 4;
        int col0 = (idx & 15) * 8;
        float alpha = lds_alpha[row];
        short8 r8 = *reinterpret_cast<const short8*>(rho_g + (row0 + row) * 128 + col0);
        size_t obase = (row0 + row) * 128 + col0;
        if constexpr (DT == 1) {
            short8 pack;
#pragma unroll
            for (int j = 0; j < 8; ++j) {
                float yv = ldf<1>(z0p, col0 + j) + alpha * bf2f((unsigned short)r8[j])
                         + ldf<1>(ypp, col0 + j);
                pack[j] = (short)f2bf(yv);
            }
            *reinterpret_cast<short8*>(reinterpret_cast<unsigned short*>(outp) + obase) = pack;
        } else {
            f32x4 p0, p1;
#pragma unroll
            for (int j = 0; j < 4; ++j) {
                p0[j] = ldf<0>(z0p, col0 + j) + alpha * bf2f((unsigned short)r8[j])
                      + ldf<0>(ypp, col0 + j);
                p1[j] = ldf<0>(z0p, col0 + 4 + j) + alpha * bf2f((unsigned short)r8[4 + j])
                      + ldf<0>(ypp, col0 + 4 + j);
            }
            *reinterpret_cast<f32x4*>(reinterpret_cast<float*>(outp) + obase) = p0;
            *reinterpret_cast<f32x4*>(reinterpret_cast<float*>(outp) + obase + 4) = p1;
        }
    }
}

// ================== fallback: R6 mono kernel (ws too small) ==================
template<int DT>
__global__ __launch_bounds__(256, 2) void rayen_mono(
    const void* xp, const void* Wp, const void* bp, const void* Dp,
    const void* ypp, const void* z0p, const void* phip, const void* dltp,
    void* outp, const int* flag)
{
    if (*flag != DT) return;
    __shared__ unsigned char lds_big[49152];
    __shared__ unsigned char lds_rho[16384];
    __shared__ float lds_nsq[64][4];
    __shared__ float lds_dmax[64][4];
    __shared__ float lds_quad[64][16];
    __shared__ float lds_lin[64][16];
    __shared__ float lds_alpha[64];

    const int tid = threadIdx.x;
    const int lane = tid & 63;
    const int w = tid >> 6, hi = lane >> 4, lo = lane & 15;
    const size_t row0 = (size_t)blockIdx.x * 64;
    const unsigned char* Xb = (const unsigned char*)xp;

#pragma unroll
    for (int i = 0; i < 8; ++i) {
        int ch = i * 256 + tid;
        int row = ((ch >> 9) << 4) | (ch & 15);
        int off = (((ch >> 6) & 7) << 6) | (((ch >> 4) & 3) << 4);
        if constexpr (DT == 1)
            glds16(Xb + (row0 + row) * 512 + off, lds_big + ch * 16);
        else {
            const float* src = (const float*)xp + (row0 + row) * 256 + (off >> 1);
            *reinterpret_cast<short8*>(lds_big + ch * 16) = ld8f4(src);
        }
    }
    short8 wf[2][8];
#pragma unroll
    for (int ct = 0; ct < 2; ++ct)
#pragma unroll
        for (int kb = 0; kb < 8; ++kb)
            wf[ct][kb] = ld8<DT>(Wp, (size_t)(w * 32 + ct * 16 + lo) * 256 + kb * 32 + hi * 8);
    asm volatile("s_waitcnt vmcnt(0)" ::: "memory");
    __syncthreads();

    f32x4 acc1[2][4];
#pragma unroll
    for (int c = 0; c < 2; ++c)
#pragma unroll
        for (int r = 0; r < 4; ++r)
#pragma unroll
            for (int e = 0; e < 4; ++e) acc1[c][r][e] = 0.f;
#pragma unroll
    for (int kb = 0; kb < 8; ++kb) {
        short8 af[4];
#pragma unroll
        for (int rt = 0; rt < 4; ++rt)
            af[rt] = *reinterpret_cast<const short8*>(lds_big + (((rt << 3) | kb) << 10) + lane * 16);
#pragma unroll
        for (int ct = 0; ct < 2; ++ct)
#pragma unroll
            for (int rt = 0; rt < 4; ++rt)
                acc1[ct][rt] = __builtin_amdgcn_mfma_f32_16x16x32_bf16(af[rt], wf[ct][kb], acc1[ct][rt], 0, 0, 0);
    }
    float bv[2];
#pragma unroll
    for (int ct = 0; ct < 2; ++ct) bv[ct] = ldf<DT>(bp, w * 32 + ct * 16 + lo);
#pragma unroll
    for (int rt = 0; rt < 4; ++rt)
#pragma unroll
        for (int reg = 0; reg < 4; ++reg) {
            float s = 0.f;
#pragma unroll
            for (int ct = 0; ct < 2; ++ct) {
                float v = acc1[ct][rt][reg] + bv[ct];
                acc1[ct][rt][reg] = v;
                s += v * v;
            }
            s += __shfl_xor(s, 1); s += __shfl_xor(s, 2);
            s += __shfl_xor(s, 4); s += __shfl_xor(s, 8);
            if (lo == 0) lds_nsq[rt * 16 + hi * 4 + reg][w] = s;
        }
    __syncthreads();
#pragma unroll
    for (int rt = 0; rt < 4; ++rt)
#pragma unroll
        for (int reg = 0; reg < 4; ++reg) {
            int row = rt * 16 + hi * 4 + reg;
            float nsq = lds_nsq[row][0] + lds_nsq[row][1] + lds_nsq[row][2] + lds_nsq[row][3];
            float rinv = 1.0f / fmaxf(sqrtf(nsq), 1e-12f);
#pragma unroll
            for (int ct = 0; ct < 2; ++ct) {
                int col = w * 32 + ct * 16 + lo;
                *reinterpret_cast<unsigned short*>(
                    lds_rho + row * 256 + ((col * 2) ^ ((row & 7) << 4))) =
                    f2bf(acc1[ct][rt][reg] * rinv);
            }
        }
    __syncthreads();
    short8 af2[4][4];
#pragma unroll
    for (int rt = 0; rt < 4; ++rt)
#pragma unroll
        for (int kb = 0; kb < 4; ++kb) {
            int row = rt * 16 + lo;
            af2[rt][kb] = *reinterpret_cast<const short8*>(
                lds_rho + row * 256 + (((kb << 6) | (hi << 4)) ^ ((lo & 7) << 4)));
        }
    unsigned char* wbase = lds_big + w * 12288;
    auto stage_q = [&](int p, int b) {
        unsigned char* dst0 = wbase + b * 4096;
#pragma unroll
        for (int kb = 0; kb < 4; ++kb) {
            size_t grow; const void* base;
            if (p < 16) { base = Dp; grow = (size_t)(p * 64 + w * 16 + lo); }
            else {
                int pd = p - 16;
                base = dltp;
                grow = (size_t)((((pd >> 3) * 4 + w) * 128) + ((pd & 7) * 16 + lo));
            }
            if constexpr (DT == 1)
                glds16((const unsigned char*)base + grow * 256 + kb * 64 + hi * 16, dst0 + kb * 1024);
            else {
                const float* src = (const float*)base + grow * 128 + kb * 32 + hi * 8;
                *reinterpret_cast<short8*>(dst0 + kb * 1024 + lane * 16) = ld8f4(src);
            }
        }
    };
    f32x4 dmax[4], qsum[4];
#pragma unroll
    for (int rt = 0; rt < 4; ++rt)
#pragma unroll
        for (int e = 0; e < 4; ++e) { dmax[rt][e] = -3e38f; qsum[rt][e] = 0.f; }
    stage_q(0, 0); stage_q(1, 1);
#pragma unroll 1
    for (int p = 0; p < 48; ++p) {
        if constexpr (DT == 1) {
            if (p < 47) { asm volatile("s_waitcnt vmcnt(4)" ::: "memory"); }
            else        { asm volatile("s_waitcnt vmcnt(0)" ::: "memory"); }
        } else {
            asm volatile("s_waitcnt vmcnt(0) lgkmcnt(0)" ::: "memory");
        }
        __builtin_amdgcn_sched_barrier(0);
        if (p + 2 < 48) stage_q(p + 2, (p + 2) % 3);
        unsigned char* buf = wbase + (p % 3) * 4096;
        f32x4 acc[4];
#pragma unroll
        for (int rt = 0; rt < 4; ++rt)
#pragma unroll
            for (int e = 0; e < 4; ++e) acc[rt][e] = 0.f;
#pragma unroll
        for (int kb = 0; kb < 4; ++kb) {
            short8 bf = *reinterpret_cast<const short8*>(buf + kb * 1024 + lane * 16);
#pragma unroll
            for (int rt = 0; rt < 4; ++rt)
                acc[rt] = __builtin_amdgcn_mfma_f32_16x16x32_bf16(af2[rt][kb], bf, acc[rt], 0, 0, 0);
        }
        if (p < 16) {
#pragma unroll
            for (int rt = 0; rt < 4; ++rt)
#pragma unroll
                for (int e = 0; e < 4; ++e) dmax[rt][e] = fmaxf(dmax[rt][e], acc[rt][e]);
        } else {
            int pd = p - 16, kr = (pd & 7) << 4;
#pragma unroll
            for (int rt = 0; rt < 4; ++rt)
#pragma unroll
                for (int e = 0; e < 4; ++e) {
                    int row = rt * 16 + hi * 4 + e;
                    float rvv = bf2f(*reinterpret_cast<const unsigned short*>(
                        lds_rho + row * 256 + ((((kr + lo) * 2)) ^ ((row & 7) << 4))));
                    qsum[rt][e] += acc[rt][e] * rvv;
                }
            if ((pd & 7) == 7) {
#pragma unroll
                for (int rt = 0; rt < 4; ++rt)
#pragma unroll
                    for (int e = 0; e < 4; ++e) {
                        float s = qsum[rt][e];
                        s += __shfl_xor(s, 1); s += __shfl_xor(s, 2);
                        s += __shfl_xor(s, 4); s += __shfl_xor(s, 8);
                        if (lo == 0) lds_quad[rt * 16 + hi * 4 + e][((pd >> 3) << 2) | w] = s;
                        qsum[rt][e] = 0.f;
                    }
            }
        }
    }
#pragma unroll
    for (int rt = 0; rt < 4; ++rt)
#pragma unroll
        for (int reg = 0; reg < 4; ++reg) {
            float m = dmax[rt][reg];
            m = fmaxf(m, __shfl_xor(m, 1)); m = fmaxf(m, __shfl_xor(m, 2));
            m = fmaxf(m, __shfl_xor(m, 4)); m = fmaxf(m, __shfl_xor(m, 8));
            if (lo == 0) lds_dmax[rt * 16 + hi * 4 + reg][w] = m;
        }
    if (w == 0) {
        f32x4 accp[4];
#pragma unroll
        for (int rt = 0; rt < 4; ++rt)
#pragma unroll
            for (int e = 0; e < 4; ++e) accp[rt][e] = 0.f;
#pragma unroll
        for (int kb = 0; kb < 4; ++kb) {
            short8 bp8 = ld8<DT>(phip, (size_t)lo * 128 + kb * 32 + hi * 8);
#pragma unroll
            for (int rt = 0; rt < 4; ++rt)
                accp[rt] = __builtin_amdgcn_mfma_f32_16x16x32_bf16(af2[rt][kb], bp8, accp[rt], 0, 0, 0);
        }
#pragma unroll
        for (int rt = 0; rt < 4; ++rt)
#pragma unroll
            for (int reg = 0; reg < 4; ++reg)
                lds_lin[rt * 16 + hi * 4 + reg][lo] = accp[rt][reg];
    }
    __syncthreads();
    if (tid < 64) {
        int row = tid;
        float nsq = lds_nsq[row][0] + lds_nsq[row][1] + lds_nsq[row][2] + lds_nsq[row][3];
        float norm = sqrtf(nsq);
        float kap = fmaxf(0.f, fmaxf(fmaxf(lds_dmax[row][0], lds_dmax[row][1]),
                                     fmaxf(lds_dmax[row][2], lds_dmax[row][3])));
#pragma unroll
        for (int q = 0; q < 16; ++q)
            kap = fmaxf(kap, lds_lin[row][q] + sqrtf(fmaxf(lds_quad[row][q], 0.f)));
        lds_alpha[row] = fminf(1.0f / kap, norm);
    }
    __syncthreads();
#pragma unroll
    for (int i = 0; i < 4; ++i) {
        int idx = tid + i * 256;
        int row = idx >> 4, col0 = (idx & 15) * 8;
        float alpha = lds_alpha[row];
        short8 r8 = *reinterpret_cast<const short8*>(
            lds_rho + row * 256 + ((col0 * 2) ^ ((row & 7) << 4)));
        float yv[8];
#pragma unroll
        for (int j = 0; j < 8; ++j)
            yv[j] = ldf<DT>(z0p, col0 + j) + alpha * bf2f((unsigned short)r8[j]) + ldf<DT>(ypp, col0 + j);
        size_t obase = (row0 + row) * 128 + col0;
        if constexpr (DT == 1) {
            short8 pack;
#pragma unroll
            for (int j = 0; j < 8; ++j) pack[j] = (short)f2bf(yv[j]);
            *reinterpret_cast<short8*>(reinterpret_cast<unsigned short*>(outp) + obase) = pack;
        } else {
            f32x4 p0, p1;
#pragma unroll
            for (int j = 0; j < 4; ++j) { p0[j] = yv[j]; p1[j] = yv[4 + j]; }
            *reinterpret_cast<f32x4*>(reinterpret_cast<float*>(outp) + obase) = p0;
            *reinterpret_cast<f32x4*>(reinterpret_cast<float*>(outp) + obase + 4) = p1;
        }
    }
}

extern "C" void kernel_launch(void* const* d_in, const int* in_sizes, int n_in,
                              void* d_out, int out_size, void* d_ws, size_t ws_size,
                              hipStream_t stream) {
    const void* x    = d_in[0];
    const void* W    = d_in[1];
    const void* b    = d_in[2];
    const void* D    = d_in[3];
    // d_in[4] = NA_E (identity by construction; unused)
    const void* yp   = d_in[5];
    const void* z0   = d_in[6];
    const void* phi  = d_in[7];
    const void* dlt  = d_in[8];

    const int B = in_sizes[0] / 256;        // 32768
    const int tiles = B / 64;               // 512

    unsigned char* ws = reinterpret_cast<unsigned char*>(d_ws);
    int* flag = reinterpret_cast<int*>(ws);
    unsigned int*   kap_u = reinterpret_cast<unsigned int*>(ws + 4096);
    unsigned short* Wb    = reinterpret_cast<unsigned short*>(ws + 135168);
    unsigned short* Db    = reinterpret_cast<unsigned short*>(ws + 200704);
    unsigned short* Qb    = reinterpret_cast<unsigned short*>(ws + 462848);
    unsigned short* Pb    = reinterpret_cast<unsigned short*>(ws + 987136);
    unsigned short* rho_g = reinterpret_cast<unsigned short*>(ws + 991232);
    const size_t need = 991232 + (size_t)B * 256;   // ~9.38 MB

    detect_dtype<<<dim3(1), dim3(256), 0, stream>>>(
        reinterpret_cast<const unsigned short*>(x), flag);

    dim3 blk(256);
    if (ws_size >= need) {
        cvt_const<<<dim3((428032 / 4 + 255) / 256), blk, 0, stream>>>(
            W, D, dlt, phi, Wb, Db, Qb, Pb, flag);
        k1_vbar<0><<<dim3(tiles), blk, 0, stream>>>(x, Wb, b, rho_g, kap_u, flag);
        k1_vbar<1><<<dim3(tiles), blk, 0, stream>>>(x, Wb, b, rho_g, kap_u, flag);
        k2a_dmax<<<dim3(tiles, 4), blk, 0, stream>>>(Db, rho_g, kap_u);
        k2b_quad<<<dim3(tiles, 2), blk, 0, stream>>>(Qb, Pb, rho_g, kap_u);
        k3_out<0><<<dim3(tiles), blk, 0, stream>>>(kap_u, rho_g, z0, yp, d_out, flag);
        k3_out<1><<<dim3(tiles), blk, 0, stream>>>(kap_u, rho_g, z0, yp, d_out, flag);
    } else {
        rayen_mono<1><<<dim3(tiles), blk, 0, stream>>>(x, W, b, D, yp, z0, phi, dlt, d_out, flag);
        rayen_mono<0><<<dim3(tiles), blk, 0, stream>>>(x, W, b, D, yp, z0, phi, dlt, d_out, flag);
    }
}

// Round 15
// 108.725 us; speedup vs baseline: 1.8273x; 1.8273x over previous
//
#include <hip/hip_runtime.h>
#include <hip/hip_bf16.h>

// RAYEN ConstraintModule for MI355X (gfx950) — R14.
// B=32768, IN_DIM=256, N=K=128, M_LIN=1024, QC=16. f32 buffers (flag==0 path).
// R13 post-mortem: >128 arch VGPRs spills regardless of launch_bounds (R2/R11/R13).
// R10's k2b (120 regs, 54us) is at the ceiling; its counters (VALU 27.6% vs Mfma
// 11.6%) show the inner loop is VALU/LDS-bound on the rv-weighting. R14 keeps
// R10's geometry (one q/wave, rt=4, (256,2)) and removes VALU register-neutrally:
// (1) padded f32 transpose rv_t[128][68] in LDS -> 4x ds_read_b128 per t instead
// of 16 scalar u16 reads+converts; (2) lin via one-time MFMA on resident af2
// (accl replaces lsum exactly), extracted with one shfl at reduction.

typedef __attribute__((ext_vector_type(8))) short short8;
typedef __attribute__((ext_vector_type(4))) float f32x4;
typedef __attribute__((ext_vector_type(4))) unsigned short us4;

__device__ __forceinline__ float bf2f(unsigned short u) {
    union { unsigned int i; float f; } v; v.i = ((unsigned int)u) << 16; return v.f;
}
__device__ __forceinline__ unsigned short f2bf(float f) {
    union { float f; unsigned int i; } v; v.f = f;
    unsigned int r = v.i + 0x7FFFu + ((v.i >> 16) & 1u);  // RNE
    return (unsigned short)(r >> 16);
}

template<int DT>
__device__ __forceinline__ short8 ld8(const void* p, size_t i) {
    if constexpr (DT == 1) {
        return *reinterpret_cast<const short8*>(reinterpret_cast<const unsigned short*>(p) + i);
    } else {
        const float* f = reinterpret_cast<const float*>(p) + i;
        short8 r;
#pragma unroll
        for (int j = 0; j < 8; ++j) r[j] = (short)f2bf(f[j]);
        return r;
    }
}
template<int DT>
__device__ __forceinline__ float ldf(const void* p, int i) {
    if constexpr (DT == 1) return bf2f(reinterpret_cast<const unsigned short*>(p)[i]);
    else return reinterpret_cast<const float*>(p)[i];
}

// 8 consecutive f32 -> short8 bf16, via two vector loads
__device__ __forceinline__ short8 ld8f4(const float* f) {
    f32x4 a = *reinterpret_cast<const f32x4*>(f);
    f32x4 b = *reinterpret_cast<const f32x4*>(f + 4);
    short8 r;
#pragma unroll
    for (int j = 0; j < 4; ++j) { r[j] = (short)f2bf(a[j]); r[4 + j] = (short)f2bf(b[j]); }
    return r;
}

__device__ __forceinline__ void glds16(const void* g, void* l) {
    __builtin_amdgcn_global_load_lds(
        (const __attribute__((address_space(1))) void*)g,
        (__attribute__((address_space(3))) void*)l, 16, 0, 0);
}

__global__ void detect_dtype(const unsigned short* __restrict__ x, int* __restrict__ flag) {
    __shared__ int cnt;
    if (threadIdx.x == 0) cnt = 0;
    __syncthreads();
    float a = fabsf(bf2f(x[threadIdx.x]));
    int ok = (a > 1e-3f && a < 1e2f) ? 1 : 0;
    atomicAdd(&cnt, ok);
    __syncthreads();
    if (threadIdx.x == 0) *flag = (cnt > 200) ? 1 : 0;  // 1 = bf16, 0 = f32
}

// ===== cvt_const: W/D/delta/phi -> bf16 in ws (convert if f32, copy if bf16) =====
__global__ void cvt_const(
    const void* __restrict__ Wp, const void* __restrict__ Dp,
    const void* __restrict__ Qp, const void* __restrict__ Pp,
    unsigned short* __restrict__ Wb, unsigned short* __restrict__ Db,
    unsigned short* __restrict__ Qb, unsigned short* __restrict__ Pb,
    const int* __restrict__ flag)
{
    const int nW = 32768, nD = 131072, nQ = 262144, nP = 2048;
    int idx = blockIdx.x * 256 + threadIdx.x;      // 4 elems per thread
    int e = idx * 4;
    if (e >= nW + nD + nQ + nP) return;
    const void* src; unsigned short* dst; int off;
    if      (e < nW)           { src = Wp; dst = Wb; off = e; }
    else if (e < nW + nD)      { src = Dp; dst = Db; off = e - nW; }
    else if (e < nW + nD + nQ) { src = Qp; dst = Qb; off = e - nW - nD; }
    else                       { src = Pp; dst = Pb; off = e - nW - nD - nQ; }
    us4 out;
    if (*flag == 0) {
        f32x4 v = *reinterpret_cast<const f32x4*>(reinterpret_cast<const float*>(src) + off);
#pragma unroll
        for (int j = 0; j < 4; ++j) out[j] = f2bf(v[j]);
    } else {
        out = *reinterpret_cast<const us4*>(reinterpret_cast<const unsigned short*>(src) + off);
    }
    *reinterpret_cast<us4*>(dst + off) = out;
}

// ========== K1: v_bar -> rho (bf16, ws), kappa seeded with 1/norm ==========
template<int DT>
__global__ __launch_bounds__(256, 2) void k1_vbar(
    const void* __restrict__ xp, const unsigned short* __restrict__ Wb,
    const void* __restrict__ bp,
    unsigned short* __restrict__ rho_g, unsigned int* __restrict__ kap_u,
    const int* __restrict__ flag)
{
    if (*flag != DT) return;
    __shared__ unsigned char lds_x[32768];   // x tile bf16, frag-major
    __shared__ unsigned char lds_v[16384];   // v_bar [64][256B] unswizzled
    __shared__ float lds_nsq[64][4];

    const int tid = threadIdx.x;
    const int lane = tid & 63;
    const int w = tid >> 6, hi = lane >> 4, lo = lane & 15;
    const size_t row0 = (size_t)blockIdx.x * 64;

    // stage x tile [64][256] -> bf16 frag-major LDS
#pragma unroll
    for (int i = 0; i < 8; ++i) {
        int ch = i * 256 + tid;
        int row = ((ch >> 9) << 4) | (ch & 15);
        int off = (((ch >> 6) & 7) << 6) | (((ch >> 4) & 3) << 4);   // byte in 512B bf16 row
        if constexpr (DT == 1) {
            glds16((const unsigned char*)xp + (row0 + row) * 512 + off, lds_x + ch * 16);
        } else {
            const float* src = (const float*)xp + (row0 + row) * 256 + (off >> 1);
            *reinterpret_cast<short8*>(lds_x + ch * 16) = ld8f4(src);
        }
    }
    // W fragments from converted bf16 (overlaps staging)
    short8 wf[2][8];
#pragma unroll
    for (int ct = 0; ct < 2; ++ct)
#pragma unroll
        for (int kb = 0; kb < 8; ++kb)
            wf[ct][kb] = *reinterpret_cast<const short8*>(
                Wb + (size_t)(w * 32 + ct * 16 + lo) * 256 + kb * 32 + hi * 8);
    if constexpr (DT == 1) { asm volatile("s_waitcnt vmcnt(0)" ::: "memory"); }
    __syncthreads();

    f32x4 acc1[2][4];
#pragma unroll
    for (int c = 0; c < 2; ++c)
#pragma unroll
        for (int r = 0; r < 4; ++r)
#pragma unroll
            for (int e = 0; e < 4; ++e) acc1[c][r][e] = 0.f;
#pragma unroll
    for (int kb = 0; kb < 8; ++kb) {
        short8 af[4];
#pragma unroll
        for (int rt = 0; rt < 4; ++rt)
            af[rt] = *reinterpret_cast<const short8*>(lds_x + (((rt << 3) | kb) << 10) + lane * 16);
#pragma unroll
        for (int ct = 0; ct < 2; ++ct)
#pragma unroll
            for (int rt = 0; rt < 4; ++rt)
                acc1[ct][rt] = __builtin_amdgcn_mfma_f32_16x16x32_bf16(af[rt], wf[ct][kb], acc1[ct][rt], 0, 0, 0);
    }
    float bv[2];
#pragma unroll
    for (int ct = 0; ct < 2; ++ct) bv[ct] = ldf<DT>(bp, w * 32 + ct * 16 + lo);
#pragma unroll
    for (int rt = 0; rt < 4; ++rt)
#pragma unroll
        for (int reg = 0; reg < 4; ++reg) {
            float s = 0.f;
#pragma unroll
            for (int ct = 0; ct < 2; ++ct) {
                float v = acc1[ct][rt][reg] + bv[ct];
                acc1[ct][rt][reg] = v;
                s += v * v;
            }
            s += __shfl_xor(s, 1); s += __shfl_xor(s, 2);
            s += __shfl_xor(s, 4); s += __shfl_xor(s, 8);
            if (lo == 0) lds_nsq[rt * 16 + hi * 4 + reg][w] = s;
        }
    __syncthreads();

#pragma unroll
    for (int rt = 0; rt < 4; ++rt)
#pragma unroll
        for (int reg = 0; reg < 4; ++reg) {
            int row = rt * 16 + hi * 4 + reg;
            float nsq = lds_nsq[row][0] + lds_nsq[row][1] + lds_nsq[row][2] + lds_nsq[row][3];
            float rinv = 1.0f / fmaxf(sqrtf(nsq), 1e-12f);
#pragma unroll
            for (int ct = 0; ct < 2; ++ct) {
                int col = w * 32 + ct * 16 + lo;
                *reinterpret_cast<unsigned short*>(lds_v + row * 256 + col * 2) =
                    f2bf(acc1[ct][rt][reg] * rinv);
            }
        }
    if (tid < 64) {
        float nsq = lds_nsq[tid][0] + lds_nsq[tid][1] + lds_nsq[tid][2] + lds_nsq[tid][3];
        // alpha = min(1/kappa, norm) == 1/max(kappa, 1/norm): seed kappa with 1/norm
        kap_u[row0 + tid] = __float_as_uint(1.0f / sqrtf(nsq));
    }
    __syncthreads();
#pragma unroll
    for (int i = 0; i < 4; ++i) {
        int ch = i * 256 + tid;
        int row = ch >> 4, c16 = ch & 15;
        *reinterpret_cast<short8*>(rho_g + (row0 + row) * 128 + c16 * 8) =
            *reinterpret_cast<const short8*>(lds_v + row * 256 + c16 * 16);
    }
}

// ---- stage rho tile [64][128]bf16 into XOR-swizzled LDS ----
__device__ __forceinline__ void stage_rho(const unsigned short* rho_g, size_t row0,
                                          unsigned char* lds_rho, int tid) {
#pragma unroll
    for (int i = 0; i < 4; ++i) {
        int ch = i * 256 + tid;
        int row = ch >> 4;
        int off = (ch & 15) * 16;
        glds16((const unsigned char*)rho_g + (row0 + row) * 256 + (off ^ ((row & 7) << 4)),
               lds_rho + ch * 16);
    }
}

// ==== K2a: relu(max_m Dv) per (tile, mg) -> atomicMax kappa ====
__global__ __launch_bounds__(256, 4) void k2a_dmax(
    const unsigned short* __restrict__ Db, const unsigned short* __restrict__ rho_g,
    unsigned int* __restrict__ kap_u)
{
    __shared__ unsigned char lds_rho[16384];
    __shared__ float lds_red[64][4];
    const int tid = threadIdx.x;
    const int lane = tid & 63;
    const int w = tid >> 6, hi = lane >> 4, lo = lane & 15;
    const size_t row0 = (size_t)blockIdx.x * 64;
    const int mg = blockIdx.y;

    stage_rho(rho_g, row0, lds_rho, tid);
    asm volatile("s_waitcnt vmcnt(0)" ::: "memory");
    __syncthreads();

    short8 af2[4][4];
#pragma unroll
    for (int rt = 0; rt < 4; ++rt)
#pragma unroll
        for (int kb = 0; kb < 4; ++kb) {
            int row = rt * 16 + lo;
            af2[rt][kb] = *reinterpret_cast<const short8*>(
                lds_rho + row * 256 + (((kb << 6) | (hi << 4)) ^ ((lo & 7) << 4)));
        }

    f32x4 dmax[4];
#pragma unroll
    for (int rt = 0; rt < 4; ++rt)
#pragma unroll
        for (int e = 0; e < 4; ++e) dmax[rt][e] = -3e38f;

#pragma unroll 2
    for (int t = 0; t < 4; ++t) {
        int col = mg * 256 + w * 64 + t * 16 + lo;
        short8 bD[4];
#pragma unroll
        for (int kb = 0; kb < 4; ++kb)
            bD[kb] = *reinterpret_cast<const short8*>(Db + (size_t)col * 128 + kb * 32 + hi * 8);
        f32x4 acc[4];
#pragma unroll
        for (int rt = 0; rt < 4; ++rt)
#pragma unroll
            for (int e = 0; e < 4; ++e) acc[rt][e] = 0.f;
#pragma unroll
        for (int kb = 0; kb < 4; ++kb)
#pragma unroll
            for (int rt = 0; rt < 4; ++rt)
                acc[rt] = __builtin_amdgcn_mfma_f32_16x16x32_bf16(af2[rt][kb], bD[kb], acc[rt], 0, 0, 0);
#pragma unroll
        for (int rt = 0; rt < 4; ++rt)
#pragma unroll
            for (int e = 0; e < 4; ++e) dmax[rt][e] = fmaxf(dmax[rt][e], acc[rt][e]);
    }
#pragma unroll
    for (int rt = 0; rt < 4; ++rt)
#pragma unroll
        for (int reg = 0; reg < 4; ++reg) {
            float m = dmax[rt][reg];
            m = fmaxf(m, __shfl_xor(m, 1)); m = fmaxf(m, __shfl_xor(m, 2));
            m = fmaxf(m, __shfl_xor(m, 4)); m = fmaxf(m, __shfl_xor(m, 8));
            if (lo == 0) lds_red[rt * 16 + hi * 4 + reg][w] = m;
        }
    __syncthreads();
    if (tid < 64) {
        float m = fmaxf(fmaxf(lds_red[tid][0], lds_red[tid][1]),
                        fmaxf(lds_red[tid][2], lds_red[tid][3]));
        m = fmaxf(m, 0.f);  // relu; also keeps uint-monotone encoding valid
        atomicMax(&kap_u[row0 + tid], __float_as_uint(m));
    }
}

// == K2b: kq = rho.phi + sqrt(rho'delta rho); one q/wave (R10 geometry);
//    rv via padded f32 LDS transpose (b128 reads); lin via one-time MFMA ==
__global__ __launch_bounds__(256, 2) void k2b_quad(
    const unsigned short* __restrict__ Qb, const unsigned short* __restrict__ Pb,
    const unsigned short* __restrict__ rho_g, unsigned int* __restrict__ kap_u)
{
    __shared__ unsigned char lds_rho[16384];
    __shared__ float rv_t[128][68];              // transposed rho, f32, padded stride
    const int tid = threadIdx.x;
    const int lane = tid & 63;
    const int w = tid >> 6, hi = lane >> 4, lo = lane & 15;
    const size_t row0 = (size_t)blockIdx.x * 64;
    const int q = blockIdx.y * 4 + w;            // one q per wave

    stage_rho(rho_g, row0, lds_rho, tid);
    asm volatile("s_waitcnt vmcnt(0)" ::: "memory");
    __syncthreads();

    // build rv_t[col][row] = rho[row][col] (f32), 32 elems/thread
    {
        int row = tid >> 2;
        int c0 = (tid & 3) * 32;
#pragma unroll
        for (int jb = 0; jb < 4; ++jb) {
            int colbase = c0 + jb * 8;
            short8 v = *reinterpret_cast<const short8*>(
                lds_rho + row * 256 + ((colbase * 2) ^ ((row & 7) << 4)));
#pragma unroll
            for (int j = 0; j < 8; ++j)
                rv_t[colbase + j][row] = bf2f((unsigned short)v[j]);
        }
    }

    short8 af2[4][4];
#pragma unroll
    for (int rt = 0; rt < 4; ++rt)
#pragma unroll
        for (int kb = 0; kb < 4; ++kb) {
            int row = rt * 16 + lo;
            af2[rt][kb] = *reinterpret_cast<const short8*>(
                lds_rho + row * 256 + (((kb << 6) | (hi << 4)) ^ ((lo & 7) << 4)));
        }
    __syncthreads();   // rv_t fully built before t-loop reads

    // lin frag (once): accl[rt] C-layout row=rt*16+hi*4+e, col=q'=lo
    f32x4 accl[4];
#pragma unroll
    for (int rt = 0; rt < 4; ++rt)
#pragma unroll
        for (int e = 0; e < 4; ++e) accl[rt][e] = 0.f;
#pragma unroll
    for (int kb = 0; kb < 4; ++kb) {
        short8 bphi = *reinterpret_cast<const short8*>(
            Pb + (size_t)lo * 128 + kb * 32 + hi * 8);
#pragma unroll
        for (int rt = 0; rt < 4; ++rt)
            accl[rt] = __builtin_amdgcn_mfma_f32_16x16x32_bf16(af2[rt][kb], bphi, accl[rt], 0, 0, 0);
    }

    f32x4 qsum[4];
#pragma unroll
    for (int rt = 0; rt < 4; ++rt)
#pragma unroll
        for (int e = 0; e < 4; ++e) qsum[rt][e] = 0.f;

#pragma unroll 2
    for (int t = 0; t < 8; ++t) {
        int colk = t * 16 + lo;
        short8 bq[4];
#pragma unroll
        for (int kb = 0; kb < 4; ++kb)
            bq[kb] = *reinterpret_cast<const short8*>(
                Qb + ((size_t)q * 128 + colk) * 128 + kb * 32 + hi * 8);
        f32x4 acc[4];
#pragma unroll
        for (int rt = 0; rt < 4; ++rt)
#pragma unroll
            for (int e = 0; e < 4; ++e) acc[rt][e] = 0.f;
#pragma unroll
        for (int kb = 0; kb < 4; ++kb)
#pragma unroll
            for (int rt = 0; rt < 4; ++rt)
                acc[rt] = __builtin_amdgcn_mfma_f32_16x16x32_bf16(af2[rt][kb], bq[kb], acc[rt], 0, 0, 0);
#pragma unroll
        for (int rt = 0; rt < 4; ++rt) {
            f32x4 rv = *reinterpret_cast<const f32x4*>(&rv_t[colk][rt * 16 + hi * 4]);
#pragma unroll
            for (int e = 0; e < 4; ++e)
                qsum[rt][e] += acc[rt][e] * rv[e];
        }
    }
#pragma unroll
    for (int rt = 0; rt < 4; ++rt)
#pragma unroll
        for (int reg = 0; reg < 4; ++reg) {
            float s = qsum[rt][reg];
            s += __shfl_xor(s, 1); s += __shfl_xor(s, 2);
            s += __shfl_xor(s, 4); s += __shfl_xor(s, 8);
            float l = __shfl(accl[rt][reg], hi * 16 + q);  // lin[row][q] from lane (hi, lo=q)
            if (lo == 0) {
                float kq = fmaxf(l + sqrtf(fmaxf(s, 0.f)), 0.f);
                atomicMax(&kap_u[row0 + rt * 16 + hi * 4 + reg], __float_as_uint(kq));
            }
        }
}

// ========== K3: alpha = 1/kappa; y = z0 + alpha*rho + yp -> d_out ==========
template<int DT>
__global__ __launch_bounds__(256, 4) void k3_out(
    const unsigned int* __restrict__ kap_u, const unsigned short* __restrict__ rho_g,
    const void* __restrict__ z0p, const void* __restrict__ ypp,
    void* __restrict__ outp, const int* __restrict__ flag)
{
    if (*flag != DT) return;
    __shared__ float lds_alpha[64];
    const int tid = threadIdx.x;
    const size_t row0 = (size_t)blockIdx.x * 64;

    if (tid < 64)
        lds_alpha[tid] = 1.0f / __uint_as_float(kap_u[row0 + tid]);
    __syncthreads();
#pragma unroll
    for (int i = 0; i < 4; ++i) {
        int idx = tid + i * 256;
        int row = idx >> 4;
        int col0 = (idx & 15) * 8;
        float alpha = lds_alpha[row];
        short8 r8 = *reinterpret_cast<const short8*>(rho_g + (row0 + row) * 128 + col0);
        size_t obase = (row0 + row) * 128 + col0;
        if constexpr (DT == 1) {
            short8 pack;
#pragma unroll
            for (int j = 0; j < 8; ++j) {
                float yv = ldf<1>(z0p, col0 + j) + alpha * bf2f((unsigned short)r8[j])
                         + ldf<1>(ypp, col0 + j);
                pack[j] = (short)f2bf(yv);
            }
            *reinterpret_cast<short8*>(reinterpret_cast<unsigned short*>(outp) + obase) = pack;
        } else {
            f32x4 p0, p1;
#pragma unroll
            for (int j = 0; j < 4; ++j) {
                p0[j] = ldf<0>(z0p, col0 + j) + alpha * bf2f((unsigned short)r8[j])
                      + ldf<0>(ypp, col0 + j);
                p1[j] = ldf<0>(z0p, col0 + 4 + j) + alpha * bf2f((unsigned short)r8[4 + j])
                      + ldf<0>(ypp, col0 + 4 + j);
            }
            *reinterpret_cast<f32x4*>(reinterpret_cast<float*>(outp) + obase) = p0;
            *reinterpret_cast<f32x4*>(reinterpret_cast<float*>(outp) + obase + 4) = p1;
        }
    }
}

// ================== fallback: R6 mono kernel (ws too small) ==================
template<int DT>
__global__ __launch_bounds__(256, 2) void rayen_mono(
    const void* xp, const void* Wp, const void* bp, const void* Dp,
    const void* ypp, const void* z0p, const void* phip, const void* dltp,
    void* outp, const int* flag)
{
    if (*flag != DT) return;
    __shared__ unsigned char lds_big[49152];
    __shared__ unsigned char lds_rho[16384];
    __shared__ float lds_nsq[64][4];
    __shared__ float lds_dmax[64][4];
    __shared__ float lds_quad[64][16];
    __shared__ float lds_lin[64][16];
    __shared__ float lds_alpha[64];

    const int tid = threadIdx.x;
    const int lane = tid & 63;
    const int w = tid >> 6, hi = lane >> 4, lo = lane & 15;
    const size_t row0 = (size_t)blockIdx.x * 64;
    const unsigned char* Xb = (const unsigned char*)xp;

#pragma unroll
    for (int i = 0; i < 8; ++i) {
        int ch = i * 256 + tid;
        int row = ((ch >> 9) << 4) | (ch & 15);
        int off = (((ch >> 6) & 7) << 6) | (((ch >> 4) & 3) << 4);
        if constexpr (DT == 1)
            glds16(Xb + (row0 + row) * 512 + off, lds_big + ch * 16);
        else {
            const float* src = (const float*)xp + (row0 + row) * 256 + (off >> 1);
            *reinterpret_cast<short8*>(lds_big + ch * 16) = ld8f4(src);
        }
    }
    short8 wf[2][8];
#pragma unroll
    for (int ct = 0; ct < 2; ++ct)
#pragma unroll
        for (int kb = 0; kb < 8; ++kb)
            wf[ct][kb] = ld8<DT>(Wp, (size_t)(w * 32 + ct * 16 + lo) * 256 + kb * 32 + hi * 8);
    asm volatile("s_waitcnt vmcnt(0)" ::: "memory");
    __syncthreads();

    f32x4 acc1[2][4];
#pragma unroll
    for (int c = 0; c < 2; ++c)
#pragma unroll
        for (int r = 0; r < 4; ++r)
#pragma unroll
            for (int e = 0; e < 4; ++e) acc1[c][r][e] = 0.f;
#pragma unroll
    for (int kb = 0; kb < 8; ++kb) {
        short8 af[4];
#pragma unroll
        for (int rt = 0; rt < 4; ++rt)
            af[rt] = *reinterpret_cast<const short8*>(lds_big + (((rt << 3) | kb) << 10) + lane * 16);
#pragma unroll
        for (int ct = 0; ct < 2; ++ct)
#pragma unroll
            for (int rt = 0; rt < 4; ++rt)
                acc1[ct][rt] = __builtin_amdgcn_mfma_f32_16x16x32_bf16(af[rt], wf[ct][kb], acc1[ct][rt], 0, 0, 0);
    }
    float bv[2];
#pragma unroll
    for (int ct = 0; ct < 2; ++ct) bv[ct] = ldf<DT>(bp, w * 32 + ct * 16 + lo);
#pragma unroll
    for (int rt = 0; rt < 4; ++rt)
#pragma unroll
        for (int reg = 0; reg < 4; ++reg) {
            float s = 0.f;
#pragma unroll
            for (int ct = 0; ct < 2; ++ct) {
                float v = acc1[ct][rt][reg] + bv[ct];
                acc1[ct][rt][reg] = v;
                s += v * v;
            }
            s += __shfl_xor(s, 1); s += __shfl_xor(s, 2);
            s += __shfl_xor(s, 4); s += __shfl_xor(s, 8);
            if (lo == 0) lds_nsq[rt * 16 + hi * 4 + reg][w] = s;
        }
    __syncthreads();
#pragma unroll
    for (int rt = 0; rt < 4; ++rt)
#pragma unroll
        for (int reg = 0; reg < 4; ++reg) {
            int row = rt * 16 + hi * 4 + reg;
            float nsq = lds_nsq[row][0] + lds_nsq[row][1] + lds_nsq[row][2] + lds_nsq[row][3];
            float rinv = 1.0f / fmaxf(sqrtf(nsq), 1e-12f);
#pragma unroll
            for (int ct = 0; ct < 2; ++ct) {
                int col = w * 32 + ct * 16 + lo;
                *reinterpret_cast<unsigned short*>(
                    lds_rho + row * 256 + ((col * 2) ^ ((row & 7) << 4))) =
                    f2bf(acc1[ct][rt][reg] * rinv);
            }
        }
    __syncthreads();
    short8 af2[4][4];
#pragma unroll
    for (int rt = 0; rt < 4; ++rt)
#pragma unroll
        for (int kb = 0; kb < 4; ++kb) {
            int row = rt * 16 + lo;
            af2[rt][kb] = *reinterpret_cast<const short8*>(
                lds_rho + row * 256 + (((kb << 6) | (hi << 4)) ^ ((lo & 7) << 4)));
        }
    unsigned char* wbase = lds_big + w * 12288;
    auto stage_q = [&](int p, int b) {
        unsigned char* dst0 = wbase + b * 4096;
#pragma unroll
        for (int kb = 0; kb < 4; ++kb) {
            size_t grow; const void* base;
            if (p < 16) { base = Dp; grow = (size_t)(p * 64 + w * 16 + lo); }
            else {
                int pd = p - 16;
                base = dltp;
                grow = (size_t)((((pd >> 3) * 4 + w) * 128) + ((pd & 7) * 16 + lo));
            }
            if constexpr (DT == 1)
                glds16((const unsigned char*)base + grow * 256 + kb * 64 + hi * 16, dst0 + kb * 1024);
            else {
                const float* src = (const float*)base + grow * 128 + kb * 32 + hi * 8;
                *reinterpret_cast<short8*>(dst0 + kb * 1024 + lane * 16) = ld8f4(src);
            }
        }
    };
    f32x4 dmax[4], qsum[4];
#pragma unroll
    for (int rt = 0; rt < 4; ++rt)
#pragma unroll
        for (int e = 0; e < 4; ++e) { dmax[rt][e] = -3e38f; qsum[rt][e] = 0.f; }
    stage_q(0, 0); stage_q(1, 1);
#pragma unroll 1
    for (int p = 0; p < 48; ++p) {
        if constexpr (DT == 1) {
            if (p < 47) { asm volatile("s_waitcnt vmcnt(4)" ::: "memory"); }
            else        { asm volatile("s_waitcnt vmcnt(0)" ::: "memory"); }
        } else {
            asm volatile("s_waitcnt vmcnt(0) lgkmcnt(0)" ::: "memory");
        }
        __builtin_amdgcn_sched_barrier(0);
        if (p + 2 < 48) stage_q(p + 2, (p + 2) % 3);
        unsigned char* buf = wbase + (p % 3) * 4096;
        f32x4 acc[4];
#pragma unroll
        for (int rt = 0; rt < 4; ++rt)
#pragma unroll
            for (int e = 0; e < 4; ++e) acc[rt][e] = 0.f;
#pragma unroll
        for (int kb = 0; kb < 4; ++kb) {
            short8 bf = *reinterpret_cast<const short8*>(buf + kb * 1024 + lane * 16);
#pragma unroll
            for (int rt = 0; rt < 4; ++rt)
                acc[rt] = __builtin_amdgcn_mfma_f32_16x16x32_bf16(af2[rt][kb], bf, acc[rt], 0, 0, 0);
        }
        if (p < 16) {
#pragma unroll
            for (int rt = 0; rt < 4; ++rt)
#pragma unroll
                for (int e = 0; e < 4; ++e) dmax[rt][e] = fmaxf(dmax[rt][e], acc[rt][e]);
        } else {
            int pd = p - 16, kr = (pd & 7) << 4;
#pragma unroll
            for (int rt = 0; rt < 4; ++rt)
#pragma unroll
                for (int e = 0; e < 4; ++e) {
                    int row = rt * 16 + hi * 4 + e;
                    float rvv = bf2f(*reinterpret_cast<const unsigned short*>(
                        lds_rho + row * 256 + ((((kr + lo) * 2)) ^ ((row & 7) << 4))));
                    qsum[rt][e] += acc[rt][e] * rvv;
                }
            if ((pd & 7) == 7) {
#pragma unroll
                for (int rt = 0; rt < 4; ++rt)
#pragma unroll
                    for (int e = 0; e < 4; ++e) {
                        float s = qsum[rt][e];
                        s += __shfl_xor(s, 1); s += __shfl_xor(s, 2);
                        s += __shfl_xor(s, 4); s += __shfl_xor(s, 8);
                        if (lo == 0) lds_quad[rt * 16 + hi * 4 + e][((pd >> 3) << 2) | w] = s;
                        qsum[rt][e] = 0.f;
                    }
            }
        }
    }
#pragma unroll
    for (int rt = 0; rt < 4; ++rt)
#pragma unroll
        for (int reg = 0; reg < 4; ++reg) {
            float m = dmax[rt][reg];
            m = fmaxf(m, __shfl_xor(m, 1)); m = fmaxf(m, __shfl_xor(m, 2));
            m = fmaxf(m, __shfl_xor(m, 4)); m = fmaxf(m, __shfl_xor(m, 8));
            if (lo == 0) lds_dmax[rt * 16 + hi * 4 + reg][w] = m;
        }
    if (w == 0) {
        f32x4 accp[4];
#pragma unroll
        for (int rt = 0; rt < 4; ++rt)
#pragma unroll
            for (int e = 0; e < 4; ++e) accp[rt][e] = 0.f;
#pragma unroll
        for (int kb = 0; kb < 4; ++kb) {
            short8 bp8 = ld8<DT>(phip, (size_t)lo * 128 + kb * 32 + hi * 8);
#pragma unroll
            for (int rt = 0; rt < 4; ++rt)
                accp[rt] = __builtin_amdgcn_mfma_f32_16x16x32_bf16(af2[rt][kb], bp8, accp[rt], 0, 0, 0);
        }
#pragma unroll
        for (int rt = 0; rt < 4; ++rt)
#pragma unroll
            for (int reg = 0; reg < 4; ++reg)
                lds_lin[rt * 16 + hi * 4 + reg][lo] = accp[rt][reg];
    }
    __syncthreads();
    if (tid < 64) {
        int row = tid;
        float nsq = lds_nsq[row][0] + lds_nsq[row][1] + lds_nsq[row][2] + lds_nsq[row][3];
        float norm = sqrtf(nsq);
        float kap = fmaxf(0.f, fmaxf(fmaxf(lds_dmax[row][0], lds_dmax[row][1]),
                                     fmaxf(lds_dmax[row][2], lds_dmax[row][3])));
#pragma unroll
        for (int q = 0; q < 16; ++q)
            kap = fmaxf(kap, lds_lin[row][q] + sqrtf(fmaxf(lds_quad[row][q], 0.f)));
        lds_alpha[row] = fminf(1.0f / kap, norm);
    }
    __syncthreads();
#pragma unroll
    for (int i = 0; i < 4; ++i) {
        int idx = tid + i * 256;
        int row = idx >> 4, col0 = (idx & 15) * 8;
        float alpha = lds_alpha[row];
        short8 r8 = *reinterpret_cast<const short8*>(
            lds_rho + row * 256 + ((col0 * 2) ^ ((row & 7) << 4)));
        float yv[8];
#pragma unroll
        for (int j = 0; j < 8; ++j)
            yv[j] = ldf<DT>(z0p, col0 + j) + alpha * bf2f((unsigned short)r8[j]) + ldf<DT>(ypp, col0 + j);
        size_t obase = (row0 + row) * 128 + col0;
        if constexpr (DT == 1) {
            short8 pack;
#pragma unroll
            for (int j = 0; j < 8; ++j) pack[j] = (short)f2bf(yv[j]);
            *reinterpret_cast<short8*>(reinterpret_cast<unsigned short*>(outp) + obase) = pack;
        } else {
            f32x4 p0, p1;
#pragma unroll
            for (int j = 0; j < 4; ++j) { p0[j] = yv[j]; p1[j] = yv[4 + j]; }
            *reinterpret_cast<f32x4*>(reinterpret_cast<float*>(outp) + obase) = p0;
            *reinterpret_cast<f32x4*>(reinterpret_cast<float*>(outp) + obase + 4) = p1;
        }
    }
}

extern "C" void kernel_launch(void* const* d_in, const int* in_sizes, int n_in,
                              void* d_out, int out_size, void* d_ws, size_t ws_size,
                              hipStream_t stream) {
    const void* x    = d_in[0];
    const void* W    = d_in[1];
    const void* b    = d_in[2];
    const void* D    = d_in[3];
    // d_in[4] = NA_E (identity by construction; unused)
    const void* yp   = d_in[5];
    const void* z0   = d_in[6];
    const void* phi  = d_in[7];
    const void* dlt  = d_in[8];

    const int B = in_sizes[0] / 256;        // 32768
    const int tiles = B / 64;               // 512

    unsigned char* ws = reinterpret_cast<unsigned char*>(d_ws);
    int* flag = reinterpret_cast<int*>(ws);
    unsigned int*   kap_u = reinterpret_cast<unsigned int*>(ws + 4096);
    unsigned short* Wb    = reinterpret_cast<unsigned short*>(ws + 135168);
    unsigned short* Db    = reinterpret_cast<unsigned short*>(ws + 200704);
    unsigned short* Qb    = reinterpret_cast<unsigned short*>(ws + 462848);
    unsigned short* Pb    = reinterpret_cast<unsigned short*>(ws + 987136);
    unsigned short* rho_g = reinterpret_cast<unsigned short*>(ws + 991232);
    const size_t need = 991232 + (size_t)B * 256;   // ~9.38 MB

    detect_dtype<<<dim3(1), dim3(256), 0, stream>>>(
        reinterpret_cast<const unsigned short*>(x), flag);

    dim3 blk(256);
    if (ws_size >= need) {
        cvt_const<<<dim3((428032 / 4 + 255) / 256), blk, 0, stream>>>(
            W, D, dlt, phi, Wb, Db, Qb, Pb, flag);
        k1_vbar<0><<<dim3(tiles), blk, 0, stream>>>(x, Wb, b, rho_g, kap_u, flag);
        k1_vbar<1><<<dim3(tiles), blk, 0, stream>>>(x, Wb, b, rho_g, kap_u, flag);
        k2a_dmax<<<dim3(tiles, 4), blk, 0, stream>>>(Db, rho_g, kap_u);
        k2b_quad<<<dim3(tiles, 4), blk, 0, stream>>>(Qb, Pb, rho_g, kap_u);
        k3_out<0><<<dim3(tiles), blk, 0, stream>>>(kap_u, rho_g, z0, yp, d_out, flag);
        k3_out<1><<<dim3(tiles), blk, 0, stream>>>(kap_u, rho_g, z0, yp, d_out, flag);
    } else {
        rayen_mono<1><<<dim3(tiles), blk, 0, stream>>>(x, W, b, D, yp, z0, phi, dlt, d_out, flag);
        rayen_mono<0><<<dim3(tiles), blk, 0, stream>>>(x, W, b, D, yp, z0, phi, dlt, d_out, flag);
    }
}

// Round 16
// 102.967 us; speedup vs baseline: 1.9295x; 1.0559x over previous
//
#include <hip/hip_runtime.h>
#include <hip/hip_bf16.h>

// RAYEN ConstraintModule for MI355X (gfx950) — R15.
// B=32768, IN_DIM=256, N=K=128, M_LIN=1024, QC=16. f32 buffers (flag==0 path).
// R14 post-mortem: k2b ~87% stall; VALU/occupancy/regs all ruled out as limiter.
// R15: (1) merge k2a into k2b (grid (512,8): y<4 quad, y>=4 dmax; shared rho/af2)
// -> one dispatch, heterogeneous WG mix fills latency gaps; (2) f2bf via
// __float2bfloat16 intrinsic (compiler fuses to v_cvt_pk_bf16_f32) — k1's f32
// staging was ~5 VALU ops/element with hand-rolled RNE.

typedef __attribute__((ext_vector_type(8))) short short8;
typedef __attribute__((ext_vector_type(4))) float f32x4;
typedef __attribute__((ext_vector_type(4))) unsigned short us4;

__device__ __forceinline__ float bf2f(unsigned short u) {
    union { unsigned int i; float f; } v; v.i = ((unsigned int)u) << 16; return v.f;
}
__device__ __forceinline__ unsigned short f2bf(float f) {
    __hip_bfloat16 h = __float2bfloat16(f);   // RNE; compiler fuses pairs to cvt_pk
    return *reinterpret_cast<unsigned short*>(&h);
}

template<int DT>
__device__ __forceinline__ short8 ld8(const void* p, size_t i) {
    if constexpr (DT == 1) {
        return *reinterpret_cast<const short8*>(reinterpret_cast<const unsigned short*>(p) + i);
    } else {
        const float* f = reinterpret_cast<const float*>(p) + i;
        short8 r;
#pragma unroll
        for (int j = 0; j < 8; ++j) r[j] = (short)f2bf(f[j]);
        return r;
    }
}
template<int DT>
__device__ __forceinline__ float ldf(const void* p, int i) {
    if constexpr (DT == 1) return bf2f(reinterpret_cast<const unsigned short*>(p)[i]);
    else return reinterpret_cast<const float*>(p)[i];
}

// 8 consecutive f32 -> short8 bf16, via two vector loads + intrinsic casts
__device__ __forceinline__ short8 ld8f4(const float* f) {
    f32x4 a = *reinterpret_cast<const f32x4*>(f);
    f32x4 b = *reinterpret_cast<const f32x4*>(f + 4);
    short8 r;
#pragma unroll
    for (int j = 0; j < 4; ++j) { r[j] = (short)f2bf(a[j]); r[4 + j] = (short)f2bf(b[j]); }
    return r;
}

__device__ __forceinline__ void glds16(const void* g, void* l) {
    __builtin_amdgcn_global_load_lds(
        (const __attribute__((address_space(1))) void*)g,
        (__attribute__((address_space(3))) void*)l, 16, 0, 0);
}

__global__ void detect_dtype(const unsigned short* __restrict__ x, int* __restrict__ flag) {
    __shared__ int cnt;
    if (threadIdx.x == 0) cnt = 0;
    __syncthreads();
    float a = fabsf(bf2f(x[threadIdx.x]));
    int ok = (a > 1e-3f && a < 1e2f) ? 1 : 0;
    atomicAdd(&cnt, ok);
    __syncthreads();
    if (threadIdx.x == 0) *flag = (cnt > 200) ? 1 : 0;  // 1 = bf16, 0 = f32
}

// ===== cvt_const: W/D/delta/phi -> bf16 in ws (convert if f32, copy if bf16) =====
__global__ void cvt_const(
    const void* __restrict__ Wp, const void* __restrict__ Dp,
    const void* __restrict__ Qp, const void* __restrict__ Pp,
    unsigned short* __restrict__ Wb, unsigned short* __restrict__ Db,
    unsigned short* __restrict__ Qb, unsigned short* __restrict__ Pb,
    const int* __restrict__ flag)
{
    const int nW = 32768, nD = 131072, nQ = 262144, nP = 2048;
    int idx = blockIdx.x * 256 + threadIdx.x;      // 4 elems per thread
    int e = idx * 4;
    if (e >= nW + nD + nQ + nP) return;
    const void* src; unsigned short* dst; int off;
    if      (e < nW)           { src = Wp; dst = Wb; off = e; }
    else if (e < nW + nD)      { src = Dp; dst = Db; off = e - nW; }
    else if (e < nW + nD + nQ) { src = Qp; dst = Qb; off = e - nW - nD; }
    else                       { src = Pp; dst = Pb; off = e - nW - nD - nQ; }
    us4 out;
    if (*flag == 0) {
        f32x4 v = *reinterpret_cast<const f32x4*>(reinterpret_cast<const float*>(src) + off);
#pragma unroll
        for (int j = 0; j < 4; ++j) out[j] = f2bf(v[j]);
    } else {
        out = *reinterpret_cast<const us4*>(reinterpret_cast<const unsigned short*>(src) + off);
    }
    *reinterpret_cast<us4*>(dst + off) = out;
}

// ========== K1: v_bar -> rho (bf16, ws), kappa seeded with 1/norm ==========
template<int DT>
__global__ __launch_bounds__(256, 2) void k1_vbar(
    const void* __restrict__ xp, const unsigned short* __restrict__ Wb,
    const void* __restrict__ bp,
    unsigned short* __restrict__ rho_g, unsigned int* __restrict__ kap_u,
    const int* __restrict__ flag)
{
    if (*flag != DT) return;
    __shared__ unsigned char lds_x[32768];   // x tile bf16, frag-major
    __shared__ unsigned char lds_v[16384];   // v_bar [64][256B] unswizzled
    __shared__ float lds_nsq[64][4];

    const int tid = threadIdx.x;
    const int lane = tid & 63;
    const int w = tid >> 6, hi = lane >> 4, lo = lane & 15;
    const size_t row0 = (size_t)blockIdx.x * 64;

    // stage x tile [64][256] -> bf16 frag-major LDS
#pragma unroll
    for (int i = 0; i < 8; ++i) {
        int ch = i * 256 + tid;
        int row = ((ch >> 9) << 4) | (ch & 15);
        int off = (((ch >> 6) & 7) << 6) | (((ch >> 4) & 3) << 4);   // byte in 512B bf16 row
        if constexpr (DT == 1) {
            glds16((const unsigned char*)xp + (row0 + row) * 512 + off, lds_x + ch * 16);
        } else {
            const float* src = (const float*)xp + (row0 + row) * 256 + (off >> 1);
            *reinterpret_cast<short8*>(lds_x + ch * 16) = ld8f4(src);
        }
    }
    // W fragments from converted bf16 (overlaps staging)
    short8 wf[2][8];
#pragma unroll
    for (int ct = 0; ct < 2; ++ct)
#pragma unroll
        for (int kb = 0; kb < 8; ++kb)
            wf[ct][kb] = *reinterpret_cast<const short8*>(
                Wb + (size_t)(w * 32 + ct * 16 + lo) * 256 + kb * 32 + hi * 8);
    if constexpr (DT == 1) { asm volatile("s_waitcnt vmcnt(0)" ::: "memory"); }
    __syncthreads();

    f32x4 acc1[2][4];
#pragma unroll
    for (int c = 0; c < 2; ++c)
#pragma unroll
        for (int r = 0; r < 4; ++r)
#pragma unroll
            for (int e = 0; e < 4; ++e) acc1[c][r][e] = 0.f;
#pragma unroll
    for (int kb = 0; kb < 8; ++kb) {
        short8 af[4];
#pragma unroll
        for (int rt = 0; rt < 4; ++rt)
            af[rt] = *reinterpret_cast<const short8*>(lds_x + (((rt << 3) | kb) << 10) + lane * 16);
#pragma unroll
        for (int ct = 0; ct < 2; ++ct)
#pragma unroll
            for (int rt = 0; rt < 4; ++rt)
                acc1[ct][rt] = __builtin_amdgcn_mfma_f32_16x16x32_bf16(af[rt], wf[ct][kb], acc1[ct][rt], 0, 0, 0);
    }
    float bv[2];
#pragma unroll
    for (int ct = 0; ct < 2; ++ct) bv[ct] = ldf<DT>(bp, w * 32 + ct * 16 + lo);
#pragma unroll
    for (int rt = 0; rt < 4; ++rt)
#pragma unroll
        for (int reg = 0; reg < 4; ++reg) {
            float s = 0.f;
#pragma unroll
            for (int ct = 0; ct < 2; ++ct) {
                float v = acc1[ct][rt][reg] + bv[ct];
                acc1[ct][rt][reg] = v;
                s += v * v;
            }
            s += __shfl_xor(s, 1); s += __shfl_xor(s, 2);
            s += __shfl_xor(s, 4); s += __shfl_xor(s, 8);
            if (lo == 0) lds_nsq[rt * 16 + hi * 4 + reg][w] = s;
        }
    __syncthreads();

#pragma unroll
    for (int rt = 0; rt < 4; ++rt)
#pragma unroll
        for (int reg = 0; reg < 4; ++reg) {
            int row = rt * 16 + hi * 4 + reg;
            float nsq = lds_nsq[row][0] + lds_nsq[row][1] + lds_nsq[row][2] + lds_nsq[row][3];
            float rinv = 1.0f / fmaxf(sqrtf(nsq), 1e-12f);
#pragma unroll
            for (int ct = 0; ct < 2; ++ct) {
                int col = w * 32 + ct * 16 + lo;
                *reinterpret_cast<unsigned short*>(lds_v + row * 256 + col * 2) =
                    f2bf(acc1[ct][rt][reg] * rinv);
            }
        }
    if (tid < 64) {
        float nsq = lds_nsq[tid][0] + lds_nsq[tid][1] + lds_nsq[tid][2] + lds_nsq[tid][3];
        // alpha = min(1/kappa, norm) == 1/max(kappa, 1/norm): seed kappa with 1/norm
        kap_u[row0 + tid] = __float_as_uint(1.0f / sqrtf(nsq));
    }
    __syncthreads();
#pragma unroll
    for (int i = 0; i < 4; ++i) {
        int ch = i * 256 + tid;
        int row = ch >> 4, c16 = ch & 15;
        *reinterpret_cast<short8*>(rho_g + (row0 + row) * 128 + c16 * 8) =
            *reinterpret_cast<const short8*>(lds_v + row * 256 + c16 * 16);
    }
}

// ---- stage rho tile [64][128]bf16 into XOR-swizzled LDS ----
__device__ __forceinline__ void stage_rho(const unsigned short* rho_g, size_t row0,
                                          unsigned char* lds_rho, int tid) {
#pragma unroll
    for (int i = 0; i < 4; ++i) {
        int ch = i * 256 + tid;
        int row = ch >> 4;
        int off = (ch & 15) * 16;
        glds16((const unsigned char*)rho_g + (row0 + row) * 256 + (off ^ ((row & 7) << 4)),
               lds_rho + ch * 16);
    }
}

// ==== K2ab merged: y<4 -> quad (q-group y, one q per wave); y>=4 -> dmax (mg=y-4) ====
__global__ __launch_bounds__(256, 2) void k2ab(
    const unsigned short* __restrict__ Qb, const unsigned short* __restrict__ Pb,
    const unsigned short* __restrict__ Db,
    const unsigned short* __restrict__ rho_g, unsigned int* __restrict__ kap_u)
{
    __shared__ unsigned char lds_rho[16384];
    __shared__ float rv_t[128][68];              // quad path only
    __shared__ float lds_red[64][4];             // dmax path only
    const int tid = threadIdx.x;
    const int lane = tid & 63;
    const int w = tid >> 6, hi = lane >> 4, lo = lane & 15;
    const size_t row0 = (size_t)blockIdx.x * 64;
    const bool is_quad = (blockIdx.y < 4);

    stage_rho(rho_g, row0, lds_rho, tid);
    asm volatile("s_waitcnt vmcnt(0)" ::: "memory");
    __syncthreads();

    if (is_quad) {
        // build rv_t[col][row] = rho[row][col] (f32), 32 elems/thread
        {
            int row = tid >> 2;
            int c0 = (tid & 3) * 32;
#pragma unroll
            for (int jb = 0; jb < 4; ++jb) {
                int colbase = c0 + jb * 8;
                short8 v = *reinterpret_cast<const short8*>(
                    lds_rho + row * 256 + ((colbase * 2) ^ ((row & 7) << 4)));
#pragma unroll
                for (int j = 0; j < 8; ++j)
                    rv_t[colbase + j][row] = bf2f((unsigned short)v[j]);
            }
        }
    }

    short8 af2[4][4];
#pragma unroll
    for (int rt = 0; rt < 4; ++rt)
#pragma unroll
        for (int kb = 0; kb < 4; ++kb) {
            int row = rt * 16 + lo;
            af2[rt][kb] = *reinterpret_cast<const short8*>(
                lds_rho + row * 256 + (((kb << 6) | (hi << 4)) ^ ((lo & 7) << 4)));
        }

    if (is_quad) {
        const int q = blockIdx.y * 4 + w;            // one q per wave
        __syncthreads();   // rv_t fully built before t-loop reads

        // lin frag (once): accl[rt] C-layout row=rt*16+hi*4+e, col=q'=lo
        f32x4 accl[4];
#pragma unroll
        for (int rt = 0; rt < 4; ++rt)
#pragma unroll
            for (int e = 0; e < 4; ++e) accl[rt][e] = 0.f;
#pragma unroll
        for (int kb = 0; kb < 4; ++kb) {
            short8 bphi = *reinterpret_cast<const short8*>(
                Pb + (size_t)lo * 128 + kb * 32 + hi * 8);
#pragma unroll
            for (int rt = 0; rt < 4; ++rt)
                accl[rt] = __builtin_amdgcn_mfma_f32_16x16x32_bf16(af2[rt][kb], bphi, accl[rt], 0, 0, 0);
        }

        f32x4 qsum[4];
#pragma unroll
        for (int rt = 0; rt < 4; ++rt)
#pragma unroll
            for (int e = 0; e < 4; ++e) qsum[rt][e] = 0.f;

#pragma unroll 2
        for (int t = 0; t < 8; ++t) {
            int colk = t * 16 + lo;
            short8 bq[4];
#pragma unroll
            for (int kb = 0; kb < 4; ++kb)
                bq[kb] = *reinterpret_cast<const short8*>(
                    Qb + ((size_t)q * 128 + colk) * 128 + kb * 32 + hi * 8);
            f32x4 acc[4];
#pragma unroll
            for (int rt = 0; rt < 4; ++rt)
#pragma unroll
                for (int e = 0; e < 4; ++e) acc[rt][e] = 0.f;
#pragma unroll
            for (int kb = 0; kb < 4; ++kb)
#pragma unroll
                for (int rt = 0; rt < 4; ++rt)
                    acc[rt] = __builtin_amdgcn_mfma_f32_16x16x32_bf16(af2[rt][kb], bq[kb], acc[rt], 0, 0, 0);
#pragma unroll
            for (int rt = 0; rt < 4; ++rt) {
                f32x4 rv = *reinterpret_cast<const f32x4*>(&rv_t[colk][rt * 16 + hi * 4]);
#pragma unroll
                for (int e = 0; e < 4; ++e)
                    qsum[rt][e] += acc[rt][e] * rv[e];
            }
        }
#pragma unroll
        for (int rt = 0; rt < 4; ++rt)
#pragma unroll
            for (int reg = 0; reg < 4; ++reg) {
                float s = qsum[rt][reg];
                s += __shfl_xor(s, 1); s += __shfl_xor(s, 2);
                s += __shfl_xor(s, 4); s += __shfl_xor(s, 8);
                float l = __shfl(accl[rt][reg], hi * 16 + q);  // lin[row][q] from lane (hi, lo=q)
                if (lo == 0) {
                    float kq = fmaxf(l + sqrtf(fmaxf(s, 0.f)), 0.f);
                    atomicMax(&kap_u[row0 + rt * 16 + hi * 4 + reg], __float_as_uint(kq));
                }
            }
    } else {
        const int mg = blockIdx.y - 4;
        f32x4 dmax[4];
#pragma unroll
        for (int rt = 0; rt < 4; ++rt)
#pragma unroll
            for (int e = 0; e < 4; ++e) dmax[rt][e] = -3e38f;

#pragma unroll 2
        for (int t = 0; t < 4; ++t) {
            int col = mg * 256 + w * 64 + t * 16 + lo;
            short8 bD[4];
#pragma unroll
            for (int kb = 0; kb < 4; ++kb)
                bD[kb] = *reinterpret_cast<const short8*>(Db + (size_t)col * 128 + kb * 32 + hi * 8);
            f32x4 acc[4];
#pragma unroll
            for (int rt = 0; rt < 4; ++rt)
#pragma unroll
                for (int e = 0; e < 4; ++e) acc[rt][e] = 0.f;
#pragma unroll
            for (int kb = 0; kb < 4; ++kb)
#pragma unroll
                for (int rt = 0; rt < 4; ++rt)
                    acc[rt] = __builtin_amdgcn_mfma_f32_16x16x32_bf16(af2[rt][kb], bD[kb], acc[rt], 0, 0, 0);
#pragma unroll
            for (int rt = 0; rt < 4; ++rt)
#pragma unroll
                for (int e = 0; e < 4; ++e) dmax[rt][e] = fmaxf(dmax[rt][e], acc[rt][e]);
        }
#pragma unroll
        for (int rt = 0; rt < 4; ++rt)
#pragma unroll
            for (int reg = 0; reg < 4; ++reg) {
                float m = dmax[rt][reg];
                m = fmaxf(m, __shfl_xor(m, 1)); m = fmaxf(m, __shfl_xor(m, 2));
                m = fmaxf(m, __shfl_xor(m, 4)); m = fmaxf(m, __shfl_xor(m, 8));
                if (lo == 0) lds_red[rt * 16 + hi * 4 + reg][w] = m;
            }
        __syncthreads();
        if (tid < 64) {
            float m = fmaxf(fmaxf(lds_red[tid][0], lds_red[tid][1]),
                            fmaxf(lds_red[tid][2], lds_red[tid][3]));
            m = fmaxf(m, 0.f);  // relu; also keeps uint-monotone encoding valid
            atomicMax(&kap_u[row0 + tid], __float_as_uint(m));
        }
    }
}

// ========== K3: alpha = 1/kappa; y = z0 + alpha*rho + yp -> d_out ==========
template<int DT>
__global__ __launch_bounds__(256, 4) void k3_out(
    const unsigned int* __restrict__ kap_u, const unsigned short* __restrict__ rho_g,
    const void* __restrict__ z0p, const void* __restrict__ ypp,
    void* __restrict__ outp, const int* __restrict__ flag)
{
    if (*flag != DT) return;
    __shared__ float lds_alpha[64];
    const int tid = threadIdx.x;
    const size_t row0 = (size_t)blockIdx.x * 64;

    if (tid < 64)
        lds_alpha[tid] = 1.0f / __uint_as_float(kap_u[row0 + tid]);
    __syncthreads();
#pragma unroll
    for (int i = 0; i < 4; ++i) {
        int idx = tid + i * 256;
        int row = idx >> 4;
        int col0 = (idx & 15) * 8;
        float alpha = lds_alpha[row];
        short8 r8 = *reinterpret_cast<const short8*>(rho_g + (row0 + row) * 128 + col0);
        size_t obase = (row0 + row) * 128 + col0;
        if constexpr (DT == 1) {
            short8 pack;
#pragma unroll
            for (int j = 0; j < 8; ++j) {
                float yv = ldf<1>(z0p, col0 + j) + alpha * bf2f((unsigned short)r8[j])
                         + ldf<1>(ypp, col0 + j);
                pack[j] = (short)f2bf(yv);
            }
            *reinterpret_cast<short8*>(reinterpret_cast<unsigned short*>(outp) + obase) = pack;
        } else {
            f32x4 p0, p1;
#pragma unroll
            for (int j = 0; j < 4; ++j) {
                p0[j] = ldf<0>(z0p, col0 + j) + alpha * bf2f((unsigned short)r8[j])
                      + ldf<0>(ypp, col0 + j);
                p1[j] = ldf<0>(z0p, col0 + 4 + j) + alpha * bf2f((unsigned short)r8[4 + j])
                      + ldf<0>(ypp, col0 + 4 + j);
            }
            *reinterpret_cast<f32x4*>(reinterpret_cast<float*>(outp) + obase) = p0;
            *reinterpret_cast<f32x4*>(reinterpret_cast<float*>(outp) + obase + 4) = p1;
        }
    }
}

// ================== fallback: R6 mono kernel (ws too small) ==================
template<int DT>
__global__ __launch_bounds__(256, 2) void rayen_mono(
    const void* xp, const void* Wp, const void* bp, const void* Dp,
    const void* ypp, const void* z0p, const void* phip, const void* dltp,
    void* outp, const int* flag)
{
    if (*flag != DT) return;
    __shared__ unsigned char lds_big[49152];
    __shared__ unsigned char lds_rho[16384];
    __shared__ float lds_nsq[64][4];
    __shared__ float lds_dmax[64][4];
    __shared__ float lds_quad[64][16];
    __shared__ float lds_lin[64][16];
    __shared__ float lds_alpha[64];

    const int tid = threadIdx.x;
    const int lane = tid & 63;
    const int w = tid >> 6, hi = lane >> 4, lo = lane & 15;
    const size_t row0 = (size_t)blockIdx.x * 64;
    const unsigned char* Xb = (const unsigned char*)xp;

#pragma unroll
    for (int i = 0; i < 8; ++i) {
        int ch = i * 256 + tid;
        int row = ((ch >> 9) << 4) | (ch & 15);
        int off = (((ch >> 6) & 7) << 6) | (((ch >> 4) & 3) << 4);
        if constexpr (DT == 1)
            glds16(Xb + (row0 + row) * 512 + off, lds_big + ch * 16);
        else {
            const float* src = (const float*)xp + (row0 + row) * 256 + (off >> 1);
            *reinterpret_cast<short8*>(lds_big + ch * 16) = ld8f4(src);
        }
    }
    short8 wf[2][8];
#pragma unroll
    for (int ct = 0; ct < 2; ++ct)
#pragma unroll
        for (int kb = 0; kb < 8; ++kb)
            wf[ct][kb] = ld8<DT>(Wp, (size_t)(w * 32 + ct * 16 + lo) * 256 + kb * 32 + hi * 8);
    asm volatile("s_waitcnt vmcnt(0)" ::: "memory");
    __syncthreads();

    f32x4 acc1[2][4];
#pragma unroll
    for (int c = 0; c < 2; ++c)
#pragma unroll
        for (int r = 0; r < 4; ++r)
#pragma unroll
            for (int e = 0; e < 4; ++e) acc1[c][r][e] = 0.f;
#pragma unroll
    for (int kb = 0; kb < 8; ++kb) {
        short8 af[4];
#pragma unroll
        for (int rt = 0; rt < 4; ++rt)
            af[rt] = *reinterpret_cast<const short8*>(lds_big + (((rt << 3) | kb) << 10) + lane * 16);
#pragma unroll
        for (int ct = 0; ct < 2; ++ct)
#pragma unroll
            for (int rt = 0; rt < 4; ++rt)
                acc1[ct][rt] = __builtin_amdgcn_mfma_f32_16x16x32_bf16(af[rt], wf[ct][kb], acc1[ct][rt], 0, 0, 0);
    }
    float bv[2];
#pragma unroll
    for (int ct = 0; ct < 2; ++ct) bv[ct] = ldf<DT>(bp, w * 32 + ct * 16 + lo);
#pragma unroll
    for (int rt = 0; rt < 4; ++rt)
#pragma unroll
        for (int reg = 0; reg < 4; ++reg) {
            float s = 0.f;
#pragma unroll
            for (int ct = 0; ct < 2; ++ct) {
                float v = acc1[ct][rt][reg] + bv[ct];
                acc1[ct][rt][reg] = v;
                s += v * v;
            }
            s += __shfl_xor(s, 1); s += __shfl_xor(s, 2);
            s += __shfl_xor(s, 4); s += __shfl_xor(s, 8);
            if (lo == 0) lds_nsq[rt * 16 + hi * 4 + reg][w] = s;
        }
    __syncthreads();
#pragma unroll
    for (int rt = 0; rt < 4; ++rt)
#pragma unroll
        for (int reg = 0; reg < 4; ++reg) {
            int row = rt * 16 + hi * 4 + reg;
            float nsq = lds_nsq[row][0] + lds_nsq[row][1] + lds_nsq[row][2] + lds_nsq[row][3];
            float rinv = 1.0f / fmaxf(sqrtf(nsq), 1e-12f);
#pragma unroll
            for (int ct = 0; ct < 2; ++ct) {
                int col = w * 32 + ct * 16 + lo;
                *reinterpret_cast<unsigned short*>(
                    lds_rho + row * 256 + ((col * 2) ^ ((row & 7) << 4))) =
                    f2bf(acc1[ct][rt][reg] * rinv);
            }
        }
    __syncthreads();
    short8 af2[4][4];
#pragma unroll
    for (int rt = 0; rt < 4; ++rt)
#pragma unroll
        for (int kb = 0; kb < 4; ++kb) {
            int row = rt * 16 + lo;
            af2[rt][kb] = *reinterpret_cast<const short8*>(
                lds_rho + row * 256 + (((kb << 6) | (hi << 4)) ^ ((lo & 7) << 4)));
        }
    unsigned char* wbase = lds_big + w * 12288;
    auto stage_q = [&](int p, int b) {
        unsigned char* dst0 = wbase + b * 4096;
#pragma unroll
        for (int kb = 0; kb < 4; ++kb) {
            size_t grow; const void* base;
            if (p < 16) { base = Dp; grow = (size_t)(p * 64 + w * 16 + lo); }
            else {
                int pd = p - 16;
                base = dltp;
                grow = (size_t)((((pd >> 3) * 4 + w) * 128) + ((pd & 7) * 16 + lo));
            }
            if constexpr (DT == 1)
                glds16((const unsigned char*)base + grow * 256 + kb * 64 + hi * 16, dst0 + kb * 1024);
            else {
                const float* src = (const float*)base + grow * 128 + kb * 32 + hi * 8;
                *reinterpret_cast<short8*>(dst0 + kb * 1024 + lane * 16) = ld8f4(src);
            }
        }
    };
    f32x4 dmax[4], qsum[4];
#pragma unroll
    for (int rt = 0; rt < 4; ++rt)
#pragma unroll
        for (int e = 0; e < 4; ++e) { dmax[rt][e] = -3e38f; qsum[rt][e] = 0.f; }
    stage_q(0, 0); stage_q(1, 1);
#pragma unroll 1
    for (int p = 0; p < 48; ++p) {
        if constexpr (DT == 1) {
            if (p < 47) { asm volatile("s_waitcnt vmcnt(4)" ::: "memory"); }
            else        { asm volatile("s_waitcnt vmcnt(0)" ::: "memory"); }
        } else {
            asm volatile("s_waitcnt vmcnt(0) lgkmcnt(0)" ::: "memory");
        }
        __builtin_amdgcn_sched_barrier(0);
        if (p + 2 < 48) stage_q(p + 2, (p + 2) % 3);
        unsigned char* buf = wbase + (p % 3) * 4096;
        f32x4 acc[4];
#pragma unroll
        for (int rt = 0; rt < 4; ++rt)
#pragma unroll
            for (int e = 0; e < 4; ++e) acc[rt][e] = 0.f;
#pragma unroll
        for (int kb = 0; kb < 4; ++kb) {
            short8 bf = *reinterpret_cast<const short8*>(buf + kb * 1024 + lane * 16);
#pragma unroll
            for (int rt = 0; rt < 4; ++rt)
                acc[rt] = __builtin_amdgcn_mfma_f32_16x16x32_bf16(af2[rt][kb], bf, acc[rt], 0, 0, 0);
        }
        if (p < 16) {
#pragma unroll
            for (int rt = 0; rt < 4; ++rt)
#pragma unroll
                for (int e = 0; e < 4; ++e) dmax[rt][e] = fmaxf(dmax[rt][e], acc[rt][e]);
        } else {
            int pd = p - 16, kr = (pd & 7) << 4;
#pragma unroll
            for (int rt = 0; rt < 4; ++rt)
#pragma unroll
                for (int e = 0; e < 4; ++e) {
                    int row = rt * 16 + hi * 4 + e;
                    float rvv = bf2f(*reinterpret_cast<const unsigned short*>(
                        lds_rho + row * 256 + ((((kr + lo) * 2)) ^ ((row & 7) << 4))));
                    qsum[rt][e] += acc[rt][e] * rvv;
                }
            if ((pd & 7) == 7) {
#pragma unroll
                for (int rt = 0; rt < 4; ++rt)
#pragma unroll
                    for (int e = 0; e < 4; ++e) {
                        float s = qsum[rt][e];
                        s += __shfl_xor(s, 1); s += __shfl_xor(s, 2);
                        s += __shfl_xor(s, 4); s += __shfl_xor(s, 8);
                        if (lo == 0) lds_quad[rt * 16 + hi * 4 + e][((pd >> 3) << 2) | w] = s;
                        qsum[rt][e] = 0.f;
                    }
            }
        }
    }
#pragma unroll
    for (int rt = 0; rt < 4; ++rt)
#pragma unroll
        for (int reg = 0; reg < 4; ++reg) {
            float m = dmax[rt][reg];
            m = fmaxf(m, __shfl_xor(m, 1)); m = fmaxf(m, __shfl_xor(m, 2));
            m = fmaxf(m, __shfl_xor(m, 4)); m = fmaxf(m, __shfl_xor(m, 8));
            if (lo == 0) lds_dmax[rt * 16 + hi * 4 + reg][w] = m;
        }
    if (w == 0) {
        f32x4 accp[4];
#pragma unroll
        for (int rt = 0; rt < 4; ++rt)
#pragma unroll
            for (int e = 0; e < 4; ++e) accp[rt][e] = 0.f;
#pragma unroll
        for (int kb = 0; kb < 4; ++kb) {
            short8 bp8 = ld8<DT>(phip, (size_t)lo * 128 + kb * 32 + hi * 8);
#pragma unroll
            for (int rt = 0; rt < 4; ++rt)
                accp[rt] = __builtin_amdgcn_mfma_f32_16x16x32_bf16(af2[rt][kb], bp8, accp[rt], 0, 0, 0);
        }
#pragma unroll
        for (int rt = 0; rt < 4; ++rt)
#pragma unroll
            for (int reg = 0; reg < 4; ++reg)
                lds_lin[rt * 16 + hi * 4 + reg][lo] = accp[rt][reg];
    }
    __syncthreads();
    if (tid < 64) {
        int row = tid;
        float nsq = lds_nsq[row][0] + lds_nsq[row][1] + lds_nsq[row][2] + lds_nsq[row][3];
        float norm = sqrtf(nsq);
        float kap = fmaxf(0.f, fmaxf(fmaxf(lds_dmax[row][0], lds_dmax[row][1]),
                                     fmaxf(lds_dmax[row][2], lds_dmax[row][3])));
#pragma unroll
        for (int q = 0; q < 16; ++q)
            kap = fmaxf(kap, lds_lin[row][q] + sqrtf(fmaxf(lds_quad[row][q], 0.f)));
        lds_alpha[row] = fminf(1.0f / kap, norm);
    }
    __syncthreads();
#pragma unroll
    for (int i = 0; i < 4; ++i) {
        int idx = tid + i * 256;
        int row = idx >> 4, col0 = (idx & 15) * 8;
        float alpha = lds_alpha[row];
        short8 r8 = *reinterpret_cast<const short8*>(
            lds_rho + row * 256 + ((col0 * 2) ^ ((row & 7) << 4)));
        float yv[8];
#pragma unroll
        for (int j = 0; j < 8; ++j)
            yv[j] = ldf<DT>(z0p, col0 + j) + alpha * bf2f((unsigned short)r8[j]) + ldf<DT>(ypp, col0 + j);
        size_t obase = (row0 + row) * 128 + col0;
        if constexpr (DT == 1) {
            short8 pack;
#pragma unroll
            for (int j = 0; j < 8; ++j) pack[j] = (short)f2bf(yv[j]);
            *reinterpret_cast<short8*>(reinterpret_cast<unsigned short*>(outp) + obase) = pack;
        } else {
            f32x4 p0, p1;
#pragma unroll
            for (int j = 0; j < 4; ++j) { p0[j] = yv[j]; p1[j] = yv[4 + j]; }
            *reinterpret_cast<f32x4*>(reinterpret_cast<float*>(outp) + obase) = p0;
            *reinterpret_cast<f32x4*>(reinterpret_cast<float*>(outp) + obase + 4) = p1;
        }
    }
}

extern "C" void kernel_launch(void* const* d_in, const int* in_sizes, int n_in,
                              void* d_out, int out_size, void* d_ws, size_t ws_size,
                              hipStream_t stream) {
    const void* x    = d_in[0];
    const void* W    = d_in[1];
    const void* b    = d_in[2];
    const void* D    = d_in[3];
    // d_in[4] = NA_E (identity by construction; unused)
    const void* yp   = d_in[5];
    const void* z0   = d_in[6];
    const void* phi  = d_in[7];
    const void* dlt  = d_in[8];

    const int B = in_sizes[0] / 256;        // 32768
    const int tiles = B / 64;               // 512

    unsigned char* ws = reinterpret_cast<unsigned char*>(d_ws);
    int* flag = reinterpret_cast<int*>(ws);
    unsigned int*   kap_u = reinterpret_cast<unsigned int*>(ws + 4096);
    unsigned short* Wb    = reinterpret_cast<unsigned short*>(ws + 135168);
    unsigned short* Db    = reinterpret_cast<unsigned short*>(ws + 200704);
    unsigned short* Qb    = reinterpret_cast<unsigned short*>(ws + 462848);
    unsigned short* Pb    = reinterpret_cast<unsigned short*>(ws + 987136);
    unsigned short* rho_g = reinterpret_cast<unsigned short*>(ws + 991232);
    const size_t need = 991232 + (size_t)B * 256;   // ~9.38 MB

    detect_dtype<<<dim3(1), dim3(256), 0, stream>>>(
        reinterpret_cast<const unsigned short*>(x), flag);

    dim3 blk(256);
    if (ws_size >= need) {
        cvt_const<<<dim3((428032 / 4 + 255) / 256), blk, 0, stream>>>(
            W, D, dlt, phi, Wb, Db, Qb, Pb, flag);
        k1_vbar<0><<<dim3(tiles), blk, 0, stream>>>(x, Wb, b, rho_g, kap_u, flag);
        k1_vbar<1><<<dim3(tiles), blk, 0, stream>>>(x, Wb, b, rho_g, kap_u, flag);
        k2ab<<<dim3(tiles, 8), blk, 0, stream>>>(Qb, Pb, Db, rho_g, kap_u);
        k3_out<0><<<dim3(tiles), blk, 0, stream>>>(kap_u, rho_g, z0, yp, d_out, flag);
        k3_out<1><<<dim3(tiles), blk, 0, stream>>>(kap_u, rho_g, z0, yp, d_out, flag);
    } else {
        rayen_mono<1><<<dim3(tiles), blk, 0, stream>>>(x, W, b, D, yp, z0, phi, dlt, d_out, flag);
        rayen_mono<0><<<dim3(tiles), blk, 0, stream>>>(x, W, b, D, yp, z0, phi, dlt, d_out, flag);
    }
}